// Round 3
// baseline (363.170 us; speedup 1.0000x reference)
//
#include <hip/hip_runtime.h>
#include <hip/hip_bf16.h>
#include <math.h>
#include <stdint.h>

// ---------------------------------------------------------------------------
// Attention_17231408791684: x->QKV (bias) -> RoPE -> sliding-window(128)
// causal attention w/ sinks -> O-proj (bias).  f32 in/out, bf16 compute.
// Round 10: GEMMs rewritten as 256x256 tile, 8-wave, counted-vmcnt(8)
// double-buffer pipeline (T2 swizzle + T4 counted waits + T5 setprio).
// Stage of tile t+2 issued only after the barrier closing reads of its
// buffer; vmcnt(8) waits for the 1-ahead tile only (never drains).
// LDS frag reads XOR-swizzled (row&7)<<4 via inverse-swizzled global
// source (gld_lds dest linear, rule #21). qkv: 8x20=160 blocks;
// oproj: split-K=2, 8x12x2=192 blocks. attn/convert/reduce unchanged.
// ---------------------------------------------------------------------------

typedef __bf16 bf16x8 __attribute__((ext_vector_type(8)));
typedef float  f32x4  __attribute__((ext_vector_type(4)));
typedef uint32_t u32x4 __attribute__((ext_vector_type(4)));

#define MFMA_BF16(a,b,c) __builtin_amdgcn_mfma_f32_16x16x32_bf16((a),(b),(c),0,0,0)

// workspace element offsets (bf16 elements)
#define XB   0L
#define WQB  5898240L
#define WKB  17694720L
#define WVB  19169280L
#define WOB  20643840L
#define QB   32440320L
#define KB   40828928L
#define VB   41877504L

__device__ __forceinline__ void gld_lds16(const void* g, void* l) {
    __builtin_amdgcn_global_load_lds(
        (__attribute__((address_space(1))) void*)(g),
        (__attribute__((address_space(3))) void*)(l), 16, 0, 0);
}

__device__ __forceinline__ bf16x8 ld8f(const float* p) {
    f32x4 a = *(const f32x4*)p;
    f32x4 b = *(const f32x4*)(p + 4);
    bf16x8 r;
#pragma unroll
    for (int t = 0; t < 4; t++) { r[t] = (__bf16)a[t]; r[t + 4] = (__bf16)b[t]; }
    return r;
}

__device__ __forceinline__ uint32_t pack2(float a, float b) {
    __bf16 x = (__bf16)a, y = (__bf16)b;
    return (uint32_t)__builtin_bit_cast(unsigned short, x)
         | ((uint32_t)__builtin_bit_cast(unsigned short, y) << 16);
}

// ---------------------------------------------------------------------------
// f32 -> bf16 conversion of {x, wq, wk, wv, wo}; 8 elems/thread, 15840x256.
// ---------------------------------------------------------------------------
__global__ __launch_bounds__(256) void convert_kernel(
    const float* __restrict__ x,  const float* __restrict__ wq,
    const float* __restrict__ wk, const float* __restrict__ wv,
    const float* __restrict__ wo, __bf16* __restrict__ dst)
{
    long e = ((long)blockIdx.x * 256 + threadIdx.x) * 8;
    const float* src; long off;
    if      (e <  WQB) { src = x;  off = e; }
    else if (e <  WKB) { src = wq; off = e - WQB; }
    else if (e <  WVB) { src = wk; off = e - WKB; }
    else if (e <  WOB) { src = wv; off = e - WVB; }
    else               { src = wo; off = e - WOB; }
    *(bf16x8*)(dst + e) = ld8f(src + off);
}

// ---------------------------------------------------------------------------
// 256x256 NT GEMM, BK=64, counted-vmcnt double-buffer pipeline.
// 512 thr = 8 waves (2 wr x 4 wc); per-wave output 128x64.
// LDS per operand: [2 buf][256 rows][64 cols] bf16, linear for gld_lds;
// frag reads XOR byte-swizzled ((row&7)<<4), staged via inverse-swizzled
// GLOBAL source (involution, rule #21).
// Pipeline per tile t: {2 phases ds_read+32 MFMA} -> barrier (reads of
// buf[t&1] closed) -> stage tile t+2 into buf[t&1], vmcnt(8) (= tile t+1
// landed, t+2 still flying) -> barrier. Never drains vmcnt mid-loop.
// ---------------------------------------------------------------------------
__device__ __forceinline__ void stage256(
    const __bf16* pa0, const __bf16* pb0, const __bf16* pb1,
    const __bf16* pb2, const __bf16* pb3, size_t aStep, int kk,
    __bf16* Asb, __bf16* Bsb, int tid)
{
    gld_lds16(pa0 + kk,             Asb + (tid        ) * 8);
    gld_lds16(pa0 + aStep + kk,     Asb + (tid +  512 ) * 8);
    gld_lds16(pa0 + 2 * aStep + kk, Asb + (tid + 1024 ) * 8);
    gld_lds16(pa0 + 3 * aStep + kk, Asb + (tid + 1536 ) * 8);
    gld_lds16(pb0 + kk,             Bsb + (tid        ) * 8);
    gld_lds16(pb1 + kk,             Bsb + (tid +  512 ) * 8);
    gld_lds16(pb2 + kk,             Bsb + (tid + 1024 ) * 8);
    gld_lds16(pb3 + kk,             Bsb + (tid + 1536 ) * 8);
}

__device__ __forceinline__ void gemm256(
    const __bf16* __restrict__ A, const __bf16* __restrict__ W,
    const float* __restrict__ bias, __bf16* __restrict__ C,
    int N, int Ks, int kBeg, int kEnd, int m0, int n0,
    __bf16* As, __bf16* Bs)
{
    const int tid  = threadIdx.x;
    const int lane = tid & 63;
    const int wv   = tid >> 6;
    const int wr   = wv >> 2;         // 0..1 (m half)
    const int wc   = wv & 3;          // 0..3 (n quarter)
    const int quad = lane >> 4;
    const int c    = lane & 15;

    // staging: unit u = tid + 512*i -> LDS row u>>3, col-group u&7 (linear)
    const int srow = tid >> 3;                  // 0..63
    const int scg2 = (tid & 7) ^ (srow & 7);    // inverse-swizzled source cg

    const __bf16* pa0 = A + (size_t)(m0 + srow) * Ks + scg2 * 8;
    const size_t aStep = (size_t)64 * Ks;
    const __bf16* pb[4];
#pragma unroll
    for (int i = 0; i < 4; i++) {
        int br = n0 + srow + 64 * i; if (br > N - 1) br = N - 1;
        pb[i] = W + (size_t)br * Ks + scg2 * 8;
    }

    const int NT = (kEnd - kBeg) >> 6;          // >= 2 always here

    f32x4 acc[8][4];
#pragma unroll
    for (int i = 0; i < 8; i++)
#pragma unroll
        for (int j = 0; j < 4; j++) acc[i][j] = (f32x4){0.f, 0.f, 0.f, 0.f};

    stage256(pa0, pb[0], pb[1], pb[2], pb[3], aStep, kBeg,      As,         Bs,         tid);
    stage256(pa0, pb[0], pb[1], pb[2], pb[3], aStep, kBeg + 64, As + 16384, Bs + 16384, tid);
    asm volatile("s_waitcnt vmcnt(8)" ::: "memory");   // tile 0 landed (own wave)
    __builtin_amdgcn_sched_barrier(0);
    __builtin_amdgcn_s_barrier();                      // => tile 0 landed globally

    const int fxor = c & 7;       // frag-read swizzle (row&7 == c&7 here)

    for (int t = 0; t < NT; ++t) {
        __builtin_amdgcn_sched_barrier(0);             // no hoisting across barrier
        const __bf16* Ab = As + (t & 1) * 16384;
        const __bf16* Bb = Bs + (t & 1) * 16384;
#pragma unroll
        for (int kt = 0; kt < 2; kt++) {
            const int ko = ((kt * 4 + quad) ^ fxor) * 8;
            bf16x8 af[8], bfv[4];
#pragma unroll
            for (int i = 0; i < 8; i++)
                af[i] = *(const bf16x8*)&Ab[(wr * 128 + i * 16 + c) * 64 + ko];
#pragma unroll
            for (int j = 0; j < 4; j++)
                bfv[j] = *(const bf16x8*)&Bb[(wc * 64 + j * 16 + c) * 64 + ko];
            __builtin_amdgcn_s_setprio(1);
#pragma unroll
            for (int i = 0; i < 8; i++)
#pragma unroll
                for (int j = 0; j < 4; j++)
                    acc[i][j] = MFMA_BF16(af[i], bfv[j], acc[i][j]);
            __builtin_amdgcn_s_setprio(0);
        }
        __builtin_amdgcn_sched_barrier(0);
        __builtin_amdgcn_s_barrier();                  // reads of buf[t&1] closed
        if (t + 2 < NT) {
            stage256(pa0, pb[0], pb[1], pb[2], pb[3], aStep, kBeg + (t + 2) * 64,
                     As + (t & 1) * 16384, Bs + (t & 1) * 16384, tid);
            asm volatile("s_waitcnt vmcnt(8)" ::: "memory");  // tile t+1 landed
        } else {
            asm volatile("s_waitcnt vmcnt(0)" ::: "memory");  // drain tail
        }
        __builtin_amdgcn_sched_barrier(0);
        __builtin_amdgcn_s_barrier();                  // tile t+1 visible to all
    }

#pragma unroll
    for (int j = 0; j < 4; j++) {
        int col = n0 + wc * 64 + j * 16 + c;
        if (col >= N) continue;
        float bv = bias ? bias[col] : 0.0f;
#pragma unroll
        for (int i = 0; i < 8; i++) {
            int row = m0 + wr * 128 + i * 16 + quad * 4;
#pragma unroll
            for (int r = 0; r < 4; r++)
                C[(size_t)(row + r) * N + col] = (__bf16)(acc[i][j][r] + bv);
        }
    }
}

// Fused QKV, whole-K: grid (8,20); XCD-swizzled (160 = 8 x 20 bijective).
// wg segments: by2<16 -> q (N=4096), 16-17 -> k, 18-19 -> v.
__global__ __launch_bounds__(512, 2) void qkv_kernel(
    const __bf16* __restrict__ x,
    const __bf16* __restrict__ wq, const float* __restrict__ bq,
    const __bf16* __restrict__ wk, const float* __restrict__ bk,
    const __bf16* __restrict__ wv, const float* __restrict__ bv,
    __bf16* __restrict__ qo, __bf16* __restrict__ ko, __bf16* __restrict__ vo)
{
    __shared__ __align__(16) __bf16 As[2 * 16384], Bs[2 * 16384];  // 128 KiB
    const int lin = blockIdx.y * 8 + blockIdx.x;        // 0..159
    const int wg  = (lin & 7) * 20 + (lin >> 3);        // XCD-contiguous chunks
    const int m0  = (wg & 7) * 256;
    const int by2 = wg >> 3;                            // 0..19
    const __bf16 *W; const float* bias; __bf16* C; int N, n0;
    if (by2 < 16)      { W = wq; bias = bq; C = qo; N = 4096; n0 = by2 * 256; }
    else if (by2 < 18) { W = wk; bias = bk; C = ko; N = 512;  n0 = (by2 - 16) * 256; }
    else               { W = wv; bias = bv; C = vo; N = 512;  n0 = (by2 - 18) * 256; }
    gemm256(x, W, bias, C, N, 2880, 0, 2880, m0, n0, As, Bs);
}

// O-proj split-K=2 partials: grid (8,12,2); per-z XCD swizzle (96 = 8 x 12).
__global__ __launch_bounds__(512, 2) void oproj_kernel(
    const __bf16* __restrict__ a, const __bf16* __restrict__ w,
    __bf16* __restrict__ p0, __bf16* __restrict__ p1)
{
    __shared__ __align__(16) __bf16 As[2 * 16384], Bs[2 * 16384];  // 128 KiB
    const int z = blockIdx.z;
    __bf16* C = z ? p1 : p0;
    const int lin = blockIdx.y * 8 + blockIdx.x;        // 0..95
    const int wg  = (lin & 7) * 12 + (lin >> 3);
    const int m0  = (wg & 7) * 256;
    const int by2 = wg >> 3;                            // 0..11
    gemm256(a, w, nullptr, C, 2880, 4096, z * 2048, (z + 1) * 2048,
            m0, by2 * 256, As, Bs);
}

// out[e] = p0[e] + p1[e] + bias[col]; 8 elems/thread, grid 2880x256 exact.
__global__ __launch_bounds__(256) void reduce_kernel(
    const __bf16* __restrict__ p0, const __bf16* __restrict__ p1,
    const float* __restrict__ bo, float* __restrict__ out)
{
    long e = ((long)blockIdx.x * 256 + threadIdx.x) * 8;
    int col = (int)(e % 2880L);          // 2880 % 8 == 0: no row crossing
    bf16x8 a = *(const bf16x8*)(p0 + e);
    bf16x8 b = *(const bf16x8*)(p1 + e);
    f32x4 o0, o1;
#pragma unroll
    for (int t = 0; t < 4; t++) {
        o0[t] = (float)a[t]     + (float)b[t]     + bo[col + t];
        o1[t] = (float)a[4 + t] + (float)b[4 + t] + bo[col + 4 + t];
    }
    *(f32x4*)(out + e)     = o0;
    *(f32x4*)(out + e + 4) = o1;
}

// ---------------------------------------------------------------------------
// Attention f-step, F = 0..3 compile-time. All array indices static.
// acc9[jj] = S[key (F+jj)*16+quad*4+r][q = c] (swapped QK^T), softmax in
// lane-column group {c,c+16,c+32,c+48}, sink factor folded into P, P
// redistributed to PV A-frags via pack2 + shfl.
// ---------------------------------------------------------------------------
template<int F>
__device__ __forceinline__ void attn_f_step(
    const __bf16* __restrict__ Ks, const __bf16* __restrict__ Vt,
    __bf16* __restrict__ q, bf16x8 qf0, bf16x8 qf1,
    int i0, int h, int k0, float sk,
    int c, int quad, int laneA, int laneB, bool hiSel, int db)
{
    // ---- swapped QK^T
    f32x4 acc9[9];
#pragma unroll
    for (int jj = 0; jj < 9; jj++) acc9[jj] = (f32x4){0.f, 0.f, 0.f, 0.f};
    __builtin_amdgcn_s_setprio(1);
#pragma unroll
    for (int jj = 0; jj < 9; jj++) {
        const int j = F + jj;
        bf16x8 kf0 = *(const bf16x8*)&Ks[(j * 16 + c) * 72 + quad * 8];
        bf16x8 kf1 = *(const bf16x8*)&Ks[(j * 16 + c) * 72 + 32 + quad * 8];
        acc9[jj] = MFMA_BF16(kf0, qf0, acc9[jj]);
        acc9[jj] = MFMA_BF16(kf1, qf1, acc9[jj]);
    }
    __builtin_amdgcn_s_setprio(0);

    // ---- mask + row max (d = ig - jg; valid iff 0<=d<128 && jg>=0)
    const int jgb = k0 + F * 16 + quad * 4;
    float rmax = -3.0e4f;
#pragma unroll
    for (int jj = 0; jj < 9; jj++)
#pragma unroll
        for (int r = 0; r < 4; r++) {
            int d  = db  - jj * 16 - r;
            int jg = jgb + jj * 16 + r;
            bool ok = ((unsigned)d < 128u) && (jg >= 0);
            float vv = ok ? acc9[jj][r] : -3.0e4f;
            acc9[jj][r] = vv;
            rmax = fmaxf(rmax, vv);
        }
    rmax = fmaxf(rmax, __shfl_xor(rmax, 16));
    rmax = fmaxf(rmax, __shfl_xor(rmax, 32));

    float rs = 0.f;
#pragma unroll
    for (int jj = 0; jj < 9; jj++)
#pragma unroll
        for (int r = 0; r < 4; r++) {
            float e = __expf(acc9[jj][r] - rmax);
            acc9[jj][r] = e;
            rs += e;
        }
    rs += __shfl_xor(rs, 16);
    rs += __shfl_xor(rs, 32);

    // rowfac = sigmoid(lse - sink) / rowsum, folded into P
    float s   = fmaxf(rs, 1e-20f);
    float lse = rmax + __logf(s);
    float fac = 1.f / ((1.f + __expf(sk - lse)) * s);

    // ---- pack P*fac to bf16 pairs into static 20-word window
    uint32_t pk[20];
#pragma unroll
    for (int t = 0; t < 20; t++) pk[t] = 0;
#pragma unroll
    for (int jj = 0; jj < 9; jj++) {
        const int li = (F & 1) ? (2 * jj + 2) : (2 * jj);
        pk[li]     = pack2(acc9[jj][0] * fac, acc9[jj][1] * fac);
        pk[li + 1] = pack2(acc9[jj][2] * fac, acc9[jj][3] * fac);
    }

    // ---- PV: rebuild A-frags via shfl (within {c,c+16,c+32,c+48})
    f32x4 acc2[4];
#pragma unroll
    for (int jd = 0; jd < 4; jd++) acc2[jd] = (f32x4){0.f, 0.f, 0.f, 0.f};
#pragma unroll
    for (int kk = 0; kk < 5; kk++) {
        const int kt = (F >> 1) + kk;        // Vt chunk (global)
        uint32_t l0  = (uint32_t)__shfl((int)pk[4 * kk],     laneA);
        uint32_t h0  = (uint32_t)__shfl((int)pk[4 * kk + 1], laneA);
        uint32_t l0b = (uint32_t)__shfl((int)pk[4 * kk],     laneB);
        uint32_t h0b = (uint32_t)__shfl((int)pk[4 * kk + 1], laneB);
        uint32_t l1  = (uint32_t)__shfl((int)pk[4 * kk + 2], laneA);
        uint32_t h1  = (uint32_t)__shfl((int)pk[4 * kk + 3], laneA);
        uint32_t l1b = (uint32_t)__shfl((int)pk[4 * kk + 2], laneB);
        uint32_t h1b = (uint32_t)__shfl((int)pk[4 * kk + 3], laneB);
        u32x4 wvv = { hiSel ? l1  : l0,  hiSel ? h1  : h0,
                      hiSel ? l1b : l0b, hiSel ? h1b : h0b };
        bf16x8 pa = __builtin_bit_cast(bf16x8, wvv);
        __builtin_amdgcn_s_setprio(1);
#pragma unroll
        for (int jd = 0; jd < 4; jd++) {
            bf16x8 bv = *(const bf16x8*)&Vt[(jd * 16 + c) * 200 + kt * 32 + quad * 8];
            acc2[jd] = MFMA_BF16(pa, bv, acc2[jd]);
        }
        __builtin_amdgcn_s_setprio(0);
    }

    // ---- store O rows of this F (sink factor already folded into P)
#pragma unroll
    for (int jd = 0; jd < 4; jd++)
#pragma unroll
        for (int r = 0; r < 4; r++)
            q[(size_t)(i0 + F * 16 + quad * 4 + r) * 4096 + h * 64 + jd * 16 + c]
                = (__bf16)acc2[jd][r];
}

// ---------------------------------------------------------------------------
// Attention, fused RoPE, in-place on q. Grid (32 q-tiles, 8 kv-heads),
// 512 threads = 8 waves; wave w = head kvh*8+w, all 64 rows of the tile.
// K (rope'd) and V^T staged ONCE per block (shared by 8 heads).
// LDS: Ks[192][72] (2-way bank), Vt[64][200] (2-way bank) = 53KB.
// ---------------------------------------------------------------------------
__global__ __launch_bounds__(512) void attn_kernel(
    __bf16* __restrict__ q, const __bf16* __restrict__ k,
    const __bf16* __restrict__ v, const float* __restrict__ sinks,
    const float* __restrict__ rope)
{
    __shared__ __align__(16) __bf16 Ks[192 * 72];
    __shared__ __align__(16) __bf16 Vt[64 * 200];

    const int tid = threadIdx.x, lane = tid & 63, w = tid >> 6;
    const int quad = lane >> 4, c = lane & 15;
    const int i0  = blockIdx.x * 64;
    const int kvh = blockIdx.y;
    const int h   = kvh * 8 + w;
    const int k0  = i0 - 128;
    const float scale = 0.16832169878499658f;   // (0.1*ln32+1)/sqrt(64)

    // ---- stage K with rope: 192 rows x 64 dims, 768 units of 16 elems
#pragma unroll
    for (int it = 0; it < 2; it++) {
        int unit = it * 512 + tid;
        if (unit < 768) {
            int krow = unit >> 2;
            int kdg  = (unit & 3) * 8;
            int j = k0 + krow; if (j < 0) j = 0;
            const __bf16* gp = k + (size_t)j * 512 + kvh * 64 + kdg;
            bf16x8 x1 = *(const bf16x8*)(gp);
            bf16x8 x2 = *(const bf16x8*)(gp + 32);
            const float* rc = rope + (size_t)j * 128 + kdg;
            bf16x8 o1, o2;
#pragma unroll
            for (int t = 0; t < 8; t++) {
                float cc = rc[t], si = rc[64 + t];
                float a = (float)x1[t], b = (float)x2[t];
                o1[t] = (__bf16)(a * cc - b * si);
                o2[t] = (__bf16)(b * cc + a * si);
            }
            *(bf16x8*)&Ks[krow * 72 + kdg]      = o1;
            *(bf16x8*)&Ks[krow * 72 + kdg + 32] = o2;
        }
    }

    // ---- stage V transposed: Vt[d][s]  (s = staged key index)
    {
        const int vrow = tid & 63;
        const int d0   = (tid >> 6) * 8;
#pragma unroll
        for (int it = 0; it < 3; it++) {
            int s = it * 64 + vrow;
            int j = k0 + s; if (j < 0) j = 0;
            bf16x8 t = *(const bf16x8*)(v + (size_t)j * 512 + kvh * 64 + d0);
#pragma unroll
            for (int u = 0; u < 8; u++) Vt[(d0 + u) * 200 + s] = t[u];
        }
    }

    // ---- Q fragments (B-operand layout: row=c), rope + scale folded in
    bf16x8 qf[4][2];
#pragma unroll
    for (int f = 0; f < 4; f++) {
        const int row = i0 + f * 16 + c;
        const __bf16* gp = q + (size_t)row * 4096 + h * 64 + quad * 8;
        bf16x8 x1 = *(const bf16x8*)(gp);
        bf16x8 x2 = *(const bf16x8*)(gp + 32);
        const float* rc = rope + (size_t)row * 128 + quad * 8;
        bf16x8 o1, o2;
#pragma unroll
        for (int t = 0; t < 8; t++) {
            float cc = rc[t] * scale, si = rc[64 + t] * scale;
            float a = (float)x1[t], b = (float)x2[t];
            o1[t] = (__bf16)(a * cc - b * si);
            o2[t] = (__bf16)(b * cc + a * si);
        }
        qf[f][0] = o1; qf[f][1] = o2;
    }

    __syncthreads();

    const float sk   = sinks[h];
    const int laneA  = ((quad & 1) << 5) + c;   // owner quad (quad&1)*2
    const int laneB  = laneA + 16;              // owner quad (quad&1)*2+1
    const bool hiSel = (quad >> 1) != 0;        // needs j = 2kt+1
    const int db     = 128 + c - quad * 4;      // ig - jg, jj/r part removed

    attn_f_step<0>(Ks, Vt, q, qf[0][0], qf[0][1], i0, h, k0, sk, c, quad, laneA, laneB, hiSel, db);
    attn_f_step<1>(Ks, Vt, q, qf[1][0], qf[1][1], i0, h, k0, sk, c, quad, laneA, laneB, hiSel, db);
    attn_f_step<2>(Ks, Vt, q, qf[2][0], qf[2][1], i0, h, k0, sk, c, quad, laneA, laneB, hiSel, db);
    attn_f_step<3>(Ks, Vt, q, qf[3][0], qf[3][1], i0, h, k0, sk, c, quad, laneA, laneB, hiSel, db);
}

// ---------------------------------------------------------------------------
extern "C" void kernel_launch(void* const* d_in, const int* in_sizes, int n_in,
                              void* d_out, int out_size, void* d_ws, size_t ws_size,
                              hipStream_t stream) {
    const float* x    = (const float*)d_in[0];
    const float* rope = (const float*)d_in[1];
    const float* wq   = (const float*)d_in[2];
    const float* bq   = (const float*)d_in[3];
    const float* wk   = (const float*)d_in[4];
    const float* bk   = (const float*)d_in[5];
    const float* wv   = (const float*)d_in[6];
    const float* bv   = (const float*)d_in[7];
    const float* wo   = (const float*)d_in[8];
    const float* bo   = (const float*)d_in[9];
    const float* sk   = (const float*)d_in[10];
    float* out = (float*)d_out;

    __bf16* wsb = (__bf16*)d_ws;
    __bf16* xb  = wsb + XB;
    __bf16* wqb = wsb + WQB;
    __bf16* wkb = wsb + WKB;
    __bf16* wvb = wsb + WVB;
    __bf16* wob = wsb + WOB;
    __bf16* qb  = wsb + QB;
    __bf16* kb  = wsb + KB;
    __bf16* vb  = wsb + VB;
    __bf16* po0 = wsb + 0L;            // oproj partials overlay dead xb/wqb
    __bf16* po1 = wsb + 5898240L;

    convert_kernel<<<15840, 256, 0, stream>>>(x, wq, wk, wv, wo, xb);
    qkv_kernel<<<dim3(8, 20), 512, 0, stream>>>(xb, wqb, bq, wkb, bk, wvb, bv,
                                                qb, kb, vb);
    attn_kernel<<<dim3(32, 8), 512, 0, stream>>>(qb, kb, vb, sk, rope);
    oproj_kernel<<<dim3(8, 12, 2), 512, 0, stream>>>(qb, wob, po0, po1);
    reduce_kernel<<<2880, 256, 0, stream>>>(po0, po1, bo, out);
}

// Round 4
// 361.303 us; speedup vs baseline: 1.0052x; 1.0052x over previous
//
#include <hip/hip_runtime.h>
#include <hip/hip_bf16.h>
#include <math.h>
#include <stdint.h>

// ---------------------------------------------------------------------------
// Attention_17231408791684: x->QKV (bias) -> RoPE -> sliding-window(128)
// causal attention w/ sinks -> O-proj (bias).  f32 in/out, bf16 compute.
// Round 11: GEMM K-loop restructured from 2-phase (r3, hit the documented
// ~880TF 2-phase ceiling) to the 4-quadrant-phase schedule (T3): each phase
// {ds_read quadrant frags | stage 1 half-tile -> barrier -> lgkmcnt(0) ->
// 16 MFMA -> barrier}; staging staggered q0:A1(t+1) q1:B1(t+1) q2:B0(t+2)
// q3:A0(t+2)+vmcnt(4) (never drains). Addressing/swizzle identical to r3
// (verified: bank conflicts = 0, absmax unchanged).
// ---------------------------------------------------------------------------

typedef __bf16 bf16x8 __attribute__((ext_vector_type(8)));
typedef float  f32x4  __attribute__((ext_vector_type(4)));
typedef uint32_t u32x4 __attribute__((ext_vector_type(4)));

#define MFMA_BF16(a,b,c) __builtin_amdgcn_mfma_f32_16x16x32_bf16((a),(b),(c),0,0,0)

// workspace element offsets (bf16 elements)
#define XB   0L
#define WQB  5898240L
#define WKB  17694720L
#define WVB  19169280L
#define WOB  20643840L
#define QB   32440320L
#define KB   40828928L
#define VB   41877504L

__device__ __forceinline__ void gld_lds16(const void* g, void* l) {
    __builtin_amdgcn_global_load_lds(
        (__attribute__((address_space(1))) void*)(g),
        (__attribute__((address_space(3))) void*)(l), 16, 0, 0);
}

__device__ __forceinline__ bf16x8 ld8f(const float* p) {
    f32x4 a = *(const f32x4*)p;
    f32x4 b = *(const f32x4*)(p + 4);
    bf16x8 r;
#pragma unroll
    for (int t = 0; t < 4; t++) { r[t] = (__bf16)a[t]; r[t + 4] = (__bf16)b[t]; }
    return r;
}

__device__ __forceinline__ uint32_t pack2(float a, float b) {
    __bf16 x = (__bf16)a, y = (__bf16)b;
    return (uint32_t)__builtin_bit_cast(unsigned short, x)
         | ((uint32_t)__builtin_bit_cast(unsigned short, y) << 16);
}

// ---------------------------------------------------------------------------
// f32 -> bf16 conversion of {x, wq, wk, wv, wo}; 8 elems/thread, 15840x256.
// ---------------------------------------------------------------------------
__global__ __launch_bounds__(256) void convert_kernel(
    const float* __restrict__ x,  const float* __restrict__ wq,
    const float* __restrict__ wk, const float* __restrict__ wv,
    const float* __restrict__ wo, __bf16* __restrict__ dst)
{
    long e = ((long)blockIdx.x * 256 + threadIdx.x) * 8;
    const float* src; long off;
    if      (e <  WQB) { src = x;  off = e; }
    else if (e <  WKB) { src = wq; off = e - WQB; }
    else if (e <  WVB) { src = wk; off = e - WKB; }
    else if (e <  WOB) { src = wv; off = e - WVB; }
    else               { src = wo; off = e - WOB; }
    *(bf16x8*)(dst + e) = ld8f(src + off);
}

// ---------------------------------------------------------------------------
// 256x256 NT GEMM, BK=64, 4-quadrant-phase pipeline.
// 512 thr = 8 waves (2 wr x 4 wc); per-wave output 128x64.
// LDS/operand: [2 dbuf][2 half][128][64] bf16 (halves: A rows, B n-rows).
// Wave wr reads only A-half wr; wave wc reads only B-half wc>>1.
// Staging: 1 half-tile (16KB, 2 gld_lds/thread) per phase; region freed by
// the lgkmcnt(0) of the last phase reading it. vmcnt(4) once/tile at q3.
// Frag reads XOR-swizzled (k-group ^ (row&7)); staged via inverse-swizzled
// global source col (LDS dest linear; involution; r3-verified, 0 conflicts).
// ---------------------------------------------------------------------------
__device__ __forceinline__ void stage_half(
    const __bf16* p0, const __bf16* p1, int kk, __bf16* dst, int tid)
{
    gld_lds16(p0 + kk, dst + tid * 8);
    gld_lds16(p1 + kk, dst + 4096 + tid * 8);
}

__device__ __forceinline__ void gemm256(
    const __bf16* __restrict__ A, const __bf16* __restrict__ W,
    const float* __restrict__ bias, __bf16* __restrict__ C,
    int N, int Ks, int kBeg, int kEnd, int m0, int n0,
    __bf16* As, __bf16* Bs)
{
    const int tid  = threadIdx.x;
    const int lane = tid & 63;
    const int wv   = tid >> 6;
    const int wr   = wv >> 2;         // 0..1 (m half)
    const int wc   = wv & 3;          // 0..3 (n quarter)
    const int quad = lane >> 4;
    const int c    = lane & 15;
    const int fxor = c & 7;
    const int lrB  = (wc & 1) * 64;   // local row base within B-half

    const int srow = tid >> 3;                  // 0..63
    const int scg  = (tid & 7) ^ (srow & 7);    // inverse-swizzled source cg

    const __bf16* pa[4]; const __bf16* pb[4];
#pragma unroll
    for (int g = 0; g < 4; g++) {
        pa[g] = A + (size_t)(m0 + g * 64 + srow) * Ks + scg * 8;
        int br = n0 + g * 64 + srow; if (br > N - 1) br = N - 1;
        pb[g] = W + (size_t)br * Ks + scg * 8;
    }

    const int NT = (kEnd - kBeg) >> 6;

    f32x4 acc[8][4];
#pragma unroll
    for (int i = 0; i < 8; i++)
#pragma unroll
        for (int j = 0; j < 4; j++) acc[i][j] = (f32x4){0.f, 0.f, 0.f, 0.f};

    // prologue: tile0 {B0,A0,A1,B1}, tile1 {B0,A0}; vmcnt keeps last 2 units
    stage_half(pb[0], pb[1], kBeg, Bs,        tid);
    stage_half(pa[0], pa[1], kBeg, As,        tid);
    stage_half(pa[2], pa[3], kBeg, As + 8192, tid);
    stage_half(pb[2], pb[3], kBeg, Bs + 8192, tid);
    if (NT > 1) {
        stage_half(pb[0], pb[1], kBeg + 64, Bs + 16384, tid);
        stage_half(pa[0], pa[1], kBeg + 64, As + 16384, tid);
        asm volatile("s_waitcnt vmcnt(4)" ::: "memory");
    } else {
        asm volatile("s_waitcnt vmcnt(0)" ::: "memory");
    }
    __builtin_amdgcn_sched_barrier(0);
    __builtin_amdgcn_s_barrier();

    bf16x8 af[4][2], bb[4][2];

    for (int t = 0; t < NT; ++t) {
        const int d = t & 1;
        const __bf16* Ab = As + d * 16384 + wr * 8192;
        const __bf16* Bb = Bs + d * 16384 + (wc >> 1) * 8192;
        __bf16* Asn = As + (d ^ 1) * 16384;   // next tile's dbuf
        __bf16* Bsn = Bs + (d ^ 1) * 16384;
        __bf16* Asc = As + d * 16384;         // tile t+2's dbuf (== current)
        __bf16* Bsc = Bs + d * 16384;
        const int kk1 = kBeg + (t + 1) * 64;
        const int kk2 = kBeg + (t + 2) * 64;

        // ---------- phase q0: read A[0-3],B[0-1]; stage A1(t+1); mfma (m0,n0)
        __builtin_amdgcn_sched_barrier(0);
#pragma unroll
        for (int m = 0; m < 4; m++)
#pragma unroll
            for (int kt = 0; kt < 2; kt++)
                af[m][kt] = *(const bf16x8*)&Ab[(m * 16 + c) * 64 + (((kt * 4 + quad) ^ fxor) * 8)];
#pragma unroll
        for (int j = 0; j < 2; j++)
#pragma unroll
            for (int kt = 0; kt < 2; kt++)
                bb[j][kt] = *(const bf16x8*)&Bb[(lrB + j * 16 + c) * 64 + (((kt * 4 + quad) ^ fxor) * 8)];
        if (t + 1 < NT) stage_half(pa[2], pa[3], kk1, Asn + 8192, tid);
        __builtin_amdgcn_sched_barrier(0);
        __builtin_amdgcn_s_barrier();
        asm volatile("s_waitcnt lgkmcnt(0)" ::: "memory");
        __builtin_amdgcn_sched_barrier(0);
        __builtin_amdgcn_s_setprio(1);
#pragma unroll
        for (int i = 0; i < 4; i++)
#pragma unroll
            for (int j = 0; j < 2; j++)
#pragma unroll
                for (int kt = 0; kt < 2; kt++)
                    acc[i][j] = MFMA_BF16(af[i][kt], bb[j][kt], acc[i][j]);
        __builtin_amdgcn_s_setprio(0);
        __builtin_amdgcn_sched_barrier(0);
        __builtin_amdgcn_s_barrier();

        // ---------- phase q1: read B[2-3]; stage B1(t+1); mfma (m0,n1)
        __builtin_amdgcn_sched_barrier(0);
#pragma unroll
        for (int j = 2; j < 4; j++)
#pragma unroll
            for (int kt = 0; kt < 2; kt++)
                bb[j][kt] = *(const bf16x8*)&Bb[(lrB + j * 16 + c) * 64 + (((kt * 4 + quad) ^ fxor) * 8)];
        if (t + 1 < NT) stage_half(pb[2], pb[3], kk1, Bsn + 8192, tid);
        __builtin_amdgcn_sched_barrier(0);
        __builtin_amdgcn_s_barrier();
        asm volatile("s_waitcnt lgkmcnt(0)" ::: "memory");
        __builtin_amdgcn_sched_barrier(0);
        __builtin_amdgcn_s_setprio(1);
#pragma unroll
        for (int i = 0; i < 4; i++)
#pragma unroll
            for (int j = 2; j < 4; j++)
#pragma unroll
                for (int kt = 0; kt < 2; kt++)
                    acc[i][j] = MFMA_BF16(af[i][kt], bb[j][kt], acc[i][j]);
        __builtin_amdgcn_s_setprio(0);
        __builtin_amdgcn_sched_barrier(0);
        __builtin_amdgcn_s_barrier();

        // ---------- phase q2: read A[4-7]; stage B0(t+2); mfma (m1,n0)
        __builtin_amdgcn_sched_barrier(0);
#pragma unroll
        for (int m = 0; m < 4; m++)
#pragma unroll
            for (int kt = 0; kt < 2; kt++)
                af[m][kt] = *(const bf16x8*)&Ab[((m + 4) * 16 + c) * 64 + (((kt * 4 + quad) ^ fxor) * 8)];
        if (t + 2 < NT) stage_half(pb[0], pb[1], kk2, Bsc, tid);
        __builtin_amdgcn_sched_barrier(0);
        __builtin_amdgcn_s_barrier();
        asm volatile("s_waitcnt lgkmcnt(0)" ::: "memory");
        __builtin_amdgcn_sched_barrier(0);
        __builtin_amdgcn_s_setprio(1);
#pragma unroll
        for (int i = 0; i < 4; i++)
#pragma unroll
            for (int j = 0; j < 2; j++)
#pragma unroll
                for (int kt = 0; kt < 2; kt++)
                    acc[i + 4][j] = MFMA_BF16(af[i][kt], bb[j][kt], acc[i + 4][j]);
        __builtin_amdgcn_s_setprio(0);
        __builtin_amdgcn_sched_barrier(0);
        __builtin_amdgcn_s_barrier();

        // ---------- phase q3: stage A0(t+2); vmcnt(4); mfma (m1,n1)
        __builtin_amdgcn_sched_barrier(0);
        if (t + 2 < NT) {
            stage_half(pa[0], pa[1], kk2, Asc, tid);
            asm volatile("s_waitcnt vmcnt(4)" ::: "memory");
        } else if (t + 1 < NT) {
            asm volatile("s_waitcnt vmcnt(0)" ::: "memory");
        }
        __builtin_amdgcn_sched_barrier(0);
        __builtin_amdgcn_s_barrier();
        __builtin_amdgcn_sched_barrier(0);
        __builtin_amdgcn_s_setprio(1);
#pragma unroll
        for (int i = 0; i < 4; i++)
#pragma unroll
            for (int j = 2; j < 4; j++)
#pragma unroll
                for (int kt = 0; kt < 2; kt++)
                    acc[i + 4][j] = MFMA_BF16(af[i][kt], bb[j][kt], acc[i + 4][j]);
        __builtin_amdgcn_s_setprio(0);
        __builtin_amdgcn_sched_barrier(0);
        __builtin_amdgcn_s_barrier();
    }

#pragma unroll
    for (int j = 0; j < 4; j++) {
        int col = n0 + wc * 64 + j * 16 + c;
        if (col >= N) continue;
        float bv = bias ? bias[col] : 0.0f;
#pragma unroll
        for (int i = 0; i < 8; i++) {
            int row = m0 + wr * 128 + i * 16 + quad * 4;
#pragma unroll
            for (int r = 0; r < 4; r++)
                C[(size_t)(row + r) * N + col] = (__bf16)(acc[i][j][r] + bv);
        }
    }
}

// Fused QKV, whole-K: grid (8,20); XCD-swizzled (160 = 8 x 20 bijective).
__global__ __launch_bounds__(512, 2) void qkv_kernel(
    const __bf16* __restrict__ x,
    const __bf16* __restrict__ wq, const float* __restrict__ bq,
    const __bf16* __restrict__ wk, const float* __restrict__ bk,
    const __bf16* __restrict__ wv, const float* __restrict__ bv,
    __bf16* __restrict__ qo, __bf16* __restrict__ ko, __bf16* __restrict__ vo)
{
    __shared__ __align__(16) __bf16 As[2 * 16384], Bs[2 * 16384];  // 128 KiB
    const int lin = blockIdx.y * 8 + blockIdx.x;        // 0..159
    const int wg  = (lin & 7) * 20 + (lin >> 3);        // XCD-contiguous chunks
    const int m0  = (wg & 7) * 256;
    const int by2 = wg >> 3;                            // 0..19
    const __bf16 *W; const float* bias; __bf16* C; int N, n0;
    if (by2 < 16)      { W = wq; bias = bq; C = qo; N = 4096; n0 = by2 * 256; }
    else if (by2 < 18) { W = wk; bias = bk; C = ko; N = 512;  n0 = (by2 - 16) * 256; }
    else               { W = wv; bias = bv; C = vo; N = 512;  n0 = (by2 - 18) * 256; }
    gemm256(x, W, bias, C, N, 2880, 0, 2880, m0, n0, As, Bs);
}

// O-proj split-K=2 partials: grid (8,12,2); per-z XCD swizzle (96 = 8 x 12).
__global__ __launch_bounds__(512, 2) void oproj_kernel(
    const __bf16* __restrict__ a, const __bf16* __restrict__ w,
    __bf16* __restrict__ p0, __bf16* __restrict__ p1)
{
    __shared__ __align__(16) __bf16 As[2 * 16384], Bs[2 * 16384];  // 128 KiB
    const int z = blockIdx.z;
    __bf16* C = z ? p1 : p0;
    const int lin = blockIdx.y * 8 + blockIdx.x;        // 0..95
    const int wg  = (lin & 7) * 12 + (lin >> 3);
    const int m0  = (wg & 7) * 256;
    const int by2 = wg >> 3;                            // 0..11
    gemm256(a, w, nullptr, C, 2880, 4096, z * 2048, (z + 1) * 2048,
            m0, by2 * 256, As, Bs);
}

// out[e] = p0[e] + p1[e] + bias[col]; 8 elems/thread, grid 2880x256 exact.
__global__ __launch_bounds__(256) void reduce_kernel(
    const __bf16* __restrict__ p0, const __bf16* __restrict__ p1,
    const float* __restrict__ bo, float* __restrict__ out)
{
    long e = ((long)blockIdx.x * 256 + threadIdx.x) * 8;
    int col = (int)(e % 2880L);          // 2880 % 8 == 0: no row crossing
    bf16x8 a = *(const bf16x8*)(p0 + e);
    bf16x8 b = *(const bf16x8*)(p1 + e);
    f32x4 o0, o1;
#pragma unroll
    for (int t = 0; t < 4; t++) {
        o0[t] = (float)a[t]     + (float)b[t]     + bo[col + t];
        o1[t] = (float)a[4 + t] + (float)b[4 + t] + bo[col + 4 + t];
    }
    *(f32x4*)(out + e)     = o0;
    *(f32x4*)(out + e + 4) = o1;
}

// ---------------------------------------------------------------------------
// Attention f-step, F = 0..3 compile-time. All array indices static.
// acc9[jj] = S[key (F+jj)*16+quad*4+r][q = c] (swapped QK^T), softmax in
// lane-column group {c,c+16,c+32,c+48}, sink factor folded into P, P
// redistributed to PV A-frags via pack2 + shfl.
// ---------------------------------------------------------------------------
template<int F>
__device__ __forceinline__ void attn_f_step(
    const __bf16* __restrict__ Ks, const __bf16* __restrict__ Vt,
    __bf16* __restrict__ q, bf16x8 qf0, bf16x8 qf1,
    int i0, int h, int k0, float sk,
    int c, int quad, int laneA, int laneB, bool hiSel, int db)
{
    // ---- swapped QK^T
    f32x4 acc9[9];
#pragma unroll
    for (int jj = 0; jj < 9; jj++) acc9[jj] = (f32x4){0.f, 0.f, 0.f, 0.f};
    __builtin_amdgcn_s_setprio(1);
#pragma unroll
    for (int jj = 0; jj < 9; jj++) {
        const int j = F + jj;
        bf16x8 kf0 = *(const bf16x8*)&Ks[(j * 16 + c) * 72 + quad * 8];
        bf16x8 kf1 = *(const bf16x8*)&Ks[(j * 16 + c) * 72 + 32 + quad * 8];
        acc9[jj] = MFMA_BF16(kf0, qf0, acc9[jj]);
        acc9[jj] = MFMA_BF16(kf1, qf1, acc9[jj]);
    }
    __builtin_amdgcn_s_setprio(0);

    // ---- mask + row max (d = ig - jg; valid iff 0<=d<128 && jg>=0)
    const int jgb = k0 + F * 16 + quad * 4;
    float rmax = -3.0e4f;
#pragma unroll
    for (int jj = 0; jj < 9; jj++)
#pragma unroll
        for (int r = 0; r < 4; r++) {
            int d  = db  - jj * 16 - r;
            int jg = jgb + jj * 16 + r;
            bool ok = ((unsigned)d < 128u) && (jg >= 0);
            float vv = ok ? acc9[jj][r] : -3.0e4f;
            acc9[jj][r] = vv;
            rmax = fmaxf(rmax, vv);
        }
    rmax = fmaxf(rmax, __shfl_xor(rmax, 16));
    rmax = fmaxf(rmax, __shfl_xor(rmax, 32));

    float rs = 0.f;
#pragma unroll
    for (int jj = 0; jj < 9; jj++)
#pragma unroll
        for (int r = 0; r < 4; r++) {
            float e = __expf(acc9[jj][r] - rmax);
            acc9[jj][r] = e;
            rs += e;
        }
    rs += __shfl_xor(rs, 16);
    rs += __shfl_xor(rs, 32);

    // rowfac = sigmoid(lse - sink) / rowsum, folded into P
    float s   = fmaxf(rs, 1e-20f);
    float lse = rmax + __logf(s);
    float fac = 1.f / ((1.f + __expf(sk - lse)) * s);

    // ---- pack P*fac to bf16 pairs into static 20-word window
    uint32_t pk[20];
#pragma unroll
    for (int t = 0; t < 20; t++) pk[t] = 0;
#pragma unroll
    for (int jj = 0; jj < 9; jj++) {
        const int li = (F & 1) ? (2 * jj + 2) : (2 * jj);
        pk[li]     = pack2(acc9[jj][0] * fac, acc9[jj][1] * fac);
        pk[li + 1] = pack2(acc9[jj][2] * fac, acc9[jj][3] * fac);
    }

    // ---- PV: rebuild A-frags via shfl (within {c,c+16,c+32,c+48})
    f32x4 acc2[4];
#pragma unroll
    for (int jd = 0; jd < 4; jd++) acc2[jd] = (f32x4){0.f, 0.f, 0.f, 0.f};
#pragma unroll
    for (int kk = 0; kk < 5; kk++) {
        const int kt = (F >> 1) + kk;        // Vt chunk (global)
        uint32_t l0  = (uint32_t)__shfl((int)pk[4 * kk],     laneA);
        uint32_t h0  = (uint32_t)__shfl((int)pk[4 * kk + 1], laneA);
        uint32_t l0b = (uint32_t)__shfl((int)pk[4 * kk],     laneB);
        uint32_t h0b = (uint32_t)__shfl((int)pk[4 * kk + 1], laneB);
        uint32_t l1  = (uint32_t)__shfl((int)pk[4 * kk + 2], laneA);
        uint32_t h1  = (uint32_t)__shfl((int)pk[4 * kk + 3], laneA);
        uint32_t l1b = (uint32_t)__shfl((int)pk[4 * kk + 2], laneB);
        uint32_t h1b = (uint32_t)__shfl((int)pk[4 * kk + 3], laneB);
        u32x4 wvv = { hiSel ? l1  : l0,  hiSel ? h1  : h0,
                      hiSel ? l1b : l0b, hiSel ? h1b : h0b };
        bf16x8 pa = __builtin_bit_cast(bf16x8, wvv);
        __builtin_amdgcn_s_setprio(1);
#pragma unroll
        for (int jd = 0; jd < 4; jd++) {
            bf16x8 bv = *(const bf16x8*)&Vt[(jd * 16 + c) * 200 + kt * 32 + quad * 8];
            acc2[jd] = MFMA_BF16(pa, bv, acc2[jd]);
        }
        __builtin_amdgcn_s_setprio(0);
    }

    // ---- store O rows of this F (sink factor already folded into P)
#pragma unroll
    for (int jd = 0; jd < 4; jd++)
#pragma unroll
        for (int r = 0; r < 4; r++)
            q[(size_t)(i0 + F * 16 + quad * 4 + r) * 4096 + h * 64 + jd * 16 + c]
                = (__bf16)acc2[jd][r];
}

// ---------------------------------------------------------------------------
// Attention, fused RoPE, in-place on q. Grid (32 q-tiles, 8 kv-heads),
// 512 threads = 8 waves; wave w = head kvh*8+w, all 64 rows of the tile.
// K (rope'd) and V^T staged ONCE per block (shared by 8 heads).
// LDS: Ks[192][72] (2-way bank), Vt[64][200] (2-way bank) = 53KB.
// ---------------------------------------------------------------------------
__global__ __launch_bounds__(512) void attn_kernel(
    __bf16* __restrict__ q, const __bf16* __restrict__ k,
    const __bf16* __restrict__ v, const float* __restrict__ sinks,
    const float* __restrict__ rope)
{
    __shared__ __align__(16) __bf16 Ks[192 * 72];
    __shared__ __align__(16) __bf16 Vt[64 * 200];

    const int tid = threadIdx.x, lane = tid & 63, w = tid >> 6;
    const int quad = lane >> 4, c = lane & 15;
    const int i0  = blockIdx.x * 64;
    const int kvh = blockIdx.y;
    const int h   = kvh * 8 + w;
    const int k0  = i0 - 128;
    const float scale = 0.16832169878499658f;   // (0.1*ln32+1)/sqrt(64)

    // ---- stage K with rope: 192 rows x 64 dims, 768 units of 16 elems
#pragma unroll
    for (int it = 0; it < 2; it++) {
        int unit = it * 512 + tid;
        if (unit < 768) {
            int krow = unit >> 2;
            int kdg  = (unit & 3) * 8;
            int j = k0 + krow; if (j < 0) j = 0;
            const __bf16* gp = k + (size_t)j * 512 + kvh * 64 + kdg;
            bf16x8 x1 = *(const bf16x8*)(gp);
            bf16x8 x2 = *(const bf16x8*)(gp + 32);
            const float* rc = rope + (size_t)j * 128 + kdg;
            bf16x8 o1, o2;
#pragma unroll
            for (int t = 0; t < 8; t++) {
                float cc = rc[t], si = rc[64 + t];
                float a = (float)x1[t], b = (float)x2[t];
                o1[t] = (__bf16)(a * cc - b * si);
                o2[t] = (__bf16)(b * cc + a * si);
            }
            *(bf16x8*)&Ks[krow * 72 + kdg]      = o1;
            *(bf16x8*)&Ks[krow * 72 + kdg + 32] = o2;
        }
    }

    // ---- stage V transposed: Vt[d][s]  (s = staged key index)
    {
        const int vrow = tid & 63;
        const int d0   = (tid >> 6) * 8;
#pragma unroll
        for (int it = 0; it < 3; it++) {
            int s = it * 64 + vrow;
            int j = k0 + s; if (j < 0) j = 0;
            bf16x8 t = *(const bf16x8*)(v + (size_t)j * 512 + kvh * 64 + d0);
#pragma unroll
            for (int u = 0; u < 8; u++) Vt[(d0 + u) * 200 + s] = t[u];
        }
    }

    // ---- Q fragments (B-operand layout: row=c), rope + scale folded in
    bf16x8 qf[4][2];
#pragma unroll
    for (int f = 0; f < 4; f++) {
        const int row = i0 + f * 16 + c;
        const __bf16* gp = q + (size_t)row * 4096 + h * 64 + quad * 8;
        bf16x8 x1 = *(const bf16x8*)(gp);
        bf16x8 x2 = *(const bf16x8*)(gp + 32);
        const float* rc = rope + (size_t)row * 128 + quad * 8;
        bf16x8 o1, o2;
#pragma unroll
        for (int t = 0; t < 8; t++) {
            float cc = rc[t] * scale, si = rc[64 + t] * scale;
            float a = (float)x1[t], b = (float)x2[t];
            o1[t] = (__bf16)(a * cc - b * si);
            o2[t] = (__bf16)(b * cc + a * si);
        }
        qf[f][0] = o1; qf[f][1] = o2;
    }

    __syncthreads();

    const float sk   = sinks[h];
    const int laneA  = ((quad & 1) << 5) + c;   // owner quad (quad&1)*2
    const int laneB  = laneA + 16;              // owner quad (quad&1)*2+1
    const bool hiSel = (quad >> 1) != 0;        // needs j = 2kt+1
    const int db     = 128 + c - quad * 4;      // ig - jg, jj/r part removed

    attn_f_step<0>(Ks, Vt, q, qf[0][0], qf[0][1], i0, h, k0, sk, c, quad, laneA, laneB, hiSel, db);
    attn_f_step<1>(Ks, Vt, q, qf[1][0], qf[1][1], i0, h, k0, sk, c, quad, laneA, laneB, hiSel, db);
    attn_f_step<2>(Ks, Vt, q, qf[2][0], qf[2][1], i0, h, k0, sk, c, quad, laneA, laneB, hiSel, db);
    attn_f_step<3>(Ks, Vt, q, qf[3][0], qf[3][1], i0, h, k0, sk, c, quad, laneA, laneB, hiSel, db);
}

// ---------------------------------------------------------------------------
extern "C" void kernel_launch(void* const* d_in, const int* in_sizes, int n_in,
                              void* d_out, int out_size, void* d_ws, size_t ws_size,
                              hipStream_t stream) {
    const float* x    = (const float*)d_in[0];
    const float* rope = (const float*)d_in[1];
    const float* wq   = (const float*)d_in[2];
    const float* bq   = (const float*)d_in[3];
    const float* wk   = (const float*)d_in[4];
    const float* bk   = (const float*)d_in[5];
    const float* wv   = (const float*)d_in[6];
    const float* bv   = (const float*)d_in[7];
    const float* wo   = (const float*)d_in[8];
    const float* bo   = (const float*)d_in[9];
    const float* sk   = (const float*)d_in[10];
    float* out = (float*)d_out;

    __bf16* wsb = (__bf16*)d_ws;
    __bf16* xb  = wsb + XB;
    __bf16* wqb = wsb + WQB;
    __bf16* wkb = wsb + WKB;
    __bf16* wvb = wsb + WVB;
    __bf16* wob = wsb + WOB;
    __bf16* qb  = wsb + QB;
    __bf16* kb  = wsb + KB;
    __bf16* vb  = wsb + VB;
    __bf16* po0 = wsb + 0L;            // oproj partials overlay dead xb/wqb
    __bf16* po1 = wsb + 5898240L;

    convert_kernel<<<15840, 256, 0, stream>>>(x, wq, wk, wv, wo, xb);
    qkv_kernel<<<dim3(8, 20), 512, 0, stream>>>(xb, wqb, bq, wkb, bk, wvb, bv,
                                                qb, kb, vb);
    attn_kernel<<<dim3(32, 8), 512, 0, stream>>>(qb, kb, vb, sk, rope);
    oproj_kernel<<<dim3(8, 12, 2), 512, 0, stream>>>(qb, wob, po0, po1);
    reduce_kernel<<<2880, 256, 0, stream>>>(po0, po1, bo, out);
}

// Round 5
// 354.299 us; speedup vs baseline: 1.0250x; 1.0198x over previous
//
#include <hip/hip_runtime.h>
#include <hip/hip_bf16.h>
#include <math.h>
#include <stdint.h>

// ---------------------------------------------------------------------------
// Attention_17231408791684: x->QKV (bias) -> RoPE -> sliding-window(128)
// causal attention w/ sinks -> O-proj (bias).  f32 in/out, bf16 compute.
// Round 12: qkv keeps the 4-phase 256x256 pipeline with the MFMA nest
// reordered kt-outer/j-inner (r4 had kt innermost -> every 2nd MFMA was
// a depth-1 dependent chain on the same accumulator; reuse distance now
// 8). oproj reverted to the proven r2 128x128 gemm_block64 (attribution:
// qkv is visible in top-5 and carries the schedule experiment alone).
// Kill-switch: qkv >= 78us next round -> revert qkv to 128x128, stop.
// ---------------------------------------------------------------------------

typedef __bf16 bf16x8 __attribute__((ext_vector_type(8)));
typedef float  f32x4  __attribute__((ext_vector_type(4)));
typedef uint32_t u32x4 __attribute__((ext_vector_type(4)));

#define MFMA_BF16(a,b,c) __builtin_amdgcn_mfma_f32_16x16x32_bf16((a),(b),(c),0,0,0)

// workspace element offsets (bf16 elements)
#define XB   0L
#define WQB  5898240L
#define WKB  17694720L
#define WVB  19169280L
#define WOB  20643840L
#define QB   32440320L
#define KB   40828928L
#define VB   41877504L

__device__ __forceinline__ void gld_lds16(const void* g, void* l) {
    __builtin_amdgcn_global_load_lds(
        (__attribute__((address_space(1))) void*)(g),
        (__attribute__((address_space(3))) void*)(l), 16, 0, 0);
}

__device__ __forceinline__ bf16x8 ld8f(const float* p) {
    f32x4 a = *(const f32x4*)p;
    f32x4 b = *(const f32x4*)(p + 4);
    bf16x8 r;
#pragma unroll
    for (int t = 0; t < 4; t++) { r[t] = (__bf16)a[t]; r[t + 4] = (__bf16)b[t]; }
    return r;
}

__device__ __forceinline__ uint32_t pack2(float a, float b) {
    __bf16 x = (__bf16)a, y = (__bf16)b;
    return (uint32_t)__builtin_bit_cast(unsigned short, x)
         | ((uint32_t)__builtin_bit_cast(unsigned short, y) << 16);
}

// ---------------------------------------------------------------------------
// f32 -> bf16 conversion of {x, wq, wk, wv, wo}; 8 elems/thread, 15840x256.
// ---------------------------------------------------------------------------
__global__ __launch_bounds__(256) void convert_kernel(
    const float* __restrict__ x,  const float* __restrict__ wq,
    const float* __restrict__ wk, const float* __restrict__ wv,
    const float* __restrict__ wo, __bf16* __restrict__ dst)
{
    long e = ((long)blockIdx.x * 256 + threadIdx.x) * 8;
    const float* src; long off;
    if      (e <  WQB) { src = x;  off = e; }
    else if (e <  WKB) { src = wq; off = e - WQB; }
    else if (e <  WVB) { src = wk; off = e - WKB; }
    else if (e <  WOB) { src = wv; off = e - WVB; }
    else               { src = wo; off = e - WOB; }
    *(bf16x8*)(dst + e) = ld8f(src + off);
}

// ---------------------------------------------------------------------------
// 128x128 NT GEMM (r2-proven), BK=64. 256 thr (2x2 waves of 64x64).
// ---------------------------------------------------------------------------
__device__ __forceinline__ void gemm_block64(
    const __bf16* __restrict__ A, const __bf16* __restrict__ W,
    const float* __restrict__ bias, __bf16* __restrict__ C,
    int N, int Ks, int kBeg, int kEnd, int m0, int n0,
    __bf16* As, __bf16* Bs)
{
    const int tid  = threadIdx.x;
    const int lane = tid & 63;
    const int wv   = tid >> 6;
    const int wm   = (wv >> 1) * 64;
    const int wn   = (wv & 1) * 64;
    const int quad = lane >> 4;
    const int c    = lane & 15;

    const int srow = tid >> 2;          // 0..63
    const int scol = (tid & 3) * 8;     // 0,8,16,24

    int br0 = n0 + srow;      if (br0 > N - 1) br0 = N - 1;
    int br1 = n0 + 64 + srow; if (br1 > N - 1) br1 = N - 1;
    const __bf16* pa0 = A + (size_t)(m0 + srow) * Ks + scol;
    const __bf16* pa1 = A + (size_t)(m0 + 64 + srow) * Ks + scol;
    const __bf16* pb0 = W + (size_t)br0 * Ks + scol;
    const __bf16* pb1 = W + (size_t)br1 * Ks + scol;

    f32x4 acc[4][4];
#pragma unroll
    for (int i = 0; i < 4; i++)
#pragma unroll
        for (int j = 0; j < 4; j++) acc[i][j] = (f32x4){0.f, 0.f, 0.f, 0.f};

    for (int kk = kBeg; kk < kEnd; kk += 64) {
        gld_lds16(pa0 + kk,      As + tid * 8);
        gld_lds16(pa1 + kk,      As + 2048 + tid * 8);
        gld_lds16(pa0 + kk + 32, As + 4096 + tid * 8);
        gld_lds16(pa1 + kk + 32, As + 6144 + tid * 8);
        gld_lds16(pb0 + kk,      Bs + tid * 8);
        gld_lds16(pb1 + kk,      Bs + 2048 + tid * 8);
        gld_lds16(pb0 + kk + 32, Bs + 4096 + tid * 8);
        gld_lds16(pb1 + kk + 32, Bs + 6144 + tid * 8);
        __syncthreads();
        for (int kt = 0; kt < 2; kt++) {
            bf16x8 af[4], bfv[4];
#pragma unroll
            for (int i = 0; i < 4; i++)
                af[i] = *(const bf16x8*)&As[kt * 4096 + (wm + i * 16 + c) * 32 + quad * 8];
#pragma unroll
            for (int j = 0; j < 4; j++)
                bfv[j] = *(const bf16x8*)&Bs[kt * 4096 + (wn + j * 16 + c) * 32 + quad * 8];
#pragma unroll
            for (int i = 0; i < 4; i++)
#pragma unroll
                for (int j = 0; j < 4; j++)
                    acc[i][j] = MFMA_BF16(af[i], bfv[j], acc[i][j]);
        }
        __syncthreads();
    }

#pragma unroll
    for (int j = 0; j < 4; j++) {
        int col = n0 + wn + j * 16 + c;
        if (col >= N) continue;
        float bv = bias ? bias[col] : 0.0f;
#pragma unroll
        for (int i = 0; i < 4; i++) {
            int row = m0 + wm + i * 16 + quad * 4;
#pragma unroll
            for (int r = 0; r < 4; r++)
                C[(size_t)(row + r) * N + col] = (__bf16)(acc[i][j][r] + bv);
        }
    }
}

// ---------------------------------------------------------------------------
// 256x256 NT GEMM, BK=64, 4-quadrant-phase pipeline (T2+T3+T4+T5).
// 512 thr = 8 waves (2 wr x 4 wc); per-wave output 128x64.
// MFMA nest kt-outer / j-inner: consecutive MFMAs hit different
// accumulators (reuse distance 8) -- r4 had kt innermost = depth-1 chains.
// Staging staggered q0:A1(t+1) q1:B1(t+1) q2:B0(t+2) q3:A0(t+2)+vmcnt(4).
// Frag reads XOR-swizzled via inverse-swizzled global source (0 conflicts,
// r3/r4-verified).
// ---------------------------------------------------------------------------
__device__ __forceinline__ void stage_half(
    const __bf16* p0, const __bf16* p1, int kk, __bf16* dst, int tid)
{
    gld_lds16(p0 + kk, dst + tid * 8);
    gld_lds16(p1 + kk, dst + 4096 + tid * 8);
}

__device__ __forceinline__ void gemm256(
    const __bf16* __restrict__ A, const __bf16* __restrict__ W,
    const float* __restrict__ bias, __bf16* __restrict__ C,
    int N, int Ks, int kBeg, int kEnd, int m0, int n0,
    __bf16* As, __bf16* Bs)
{
    const int tid  = threadIdx.x;
    const int lane = tid & 63;
    const int wv   = tid >> 6;
    const int wr   = wv >> 2;         // 0..1 (m half)
    const int wc   = wv & 3;          // 0..3 (n quarter)
    const int quad = lane >> 4;
    const int c    = lane & 15;
    const int fxor = c & 7;
    const int lrB  = (wc & 1) * 64;   // local row base within B-half

    const int srow = tid >> 3;                  // 0..63
    const int scg  = (tid & 7) ^ (srow & 7);    // inverse-swizzled source cg

    const __bf16* pa[4]; const __bf16* pb[4];
#pragma unroll
    for (int g = 0; g < 4; g++) {
        pa[g] = A + (size_t)(m0 + g * 64 + srow) * Ks + scg * 8;
        int br = n0 + g * 64 + srow; if (br > N - 1) br = N - 1;
        pb[g] = W + (size_t)br * Ks + scg * 8;
    }

    const int NT = (kEnd - kBeg) >> 6;

    f32x4 acc[8][4];
#pragma unroll
    for (int i = 0; i < 8; i++)
#pragma unroll
        for (int j = 0; j < 4; j++) acc[i][j] = (f32x4){0.f, 0.f, 0.f, 0.f};

    // prologue: tile0 {B0,A0,A1,B1}, tile1 {B0,A0}; vmcnt(4) keeps tile1 flying
    stage_half(pb[0], pb[1], kBeg, Bs,        tid);
    stage_half(pa[0], pa[1], kBeg, As,        tid);
    stage_half(pa[2], pa[3], kBeg, As + 8192, tid);
    stage_half(pb[2], pb[3], kBeg, Bs + 8192, tid);
    if (NT > 1) {
        stage_half(pb[0], pb[1], kBeg + 64, Bs + 16384, tid);
        stage_half(pa[0], pa[1], kBeg + 64, As + 16384, tid);
        asm volatile("s_waitcnt vmcnt(4)" ::: "memory");
    } else {
        asm volatile("s_waitcnt vmcnt(0)" ::: "memory");
    }
    __builtin_amdgcn_sched_barrier(0);
    __builtin_amdgcn_s_barrier();

    bf16x8 af[4][2], bb[4][2];

    for (int t = 0; t < NT; ++t) {
        const int d = t & 1;
        const __bf16* Ab = As + d * 16384 + wr * 8192;
        const __bf16* Bb = Bs + d * 16384 + (wc >> 1) * 8192;
        __bf16* Asn = As + (d ^ 1) * 16384;   // next tile's dbuf
        __bf16* Bsn = Bs + (d ^ 1) * 16384;
        __bf16* Asc = As + d * 16384;         // tile t+2's dbuf (== current)
        __bf16* Bsc = Bs + d * 16384;
        const int kk1 = kBeg + (t + 1) * 64;
        const int kk2 = kBeg + (t + 2) * 64;

        // ---------- phase q0: read A[0-3],B[0-1]; stage A1(t+1); mfma (m0,n0)
        __builtin_amdgcn_sched_barrier(0);
#pragma unroll
        for (int m = 0; m < 4; m++)
#pragma unroll
            for (int kt = 0; kt < 2; kt++)
                af[m][kt] = *(const bf16x8*)&Ab[(m * 16 + c) * 64 + (((kt * 4 + quad) ^ fxor) * 8)];
#pragma unroll
        for (int j = 0; j < 2; j++)
#pragma unroll
            for (int kt = 0; kt < 2; kt++)
                bb[j][kt] = *(const bf16x8*)&Bb[(lrB + j * 16 + c) * 64 + (((kt * 4 + quad) ^ fxor) * 8)];
        if (t + 1 < NT) stage_half(pa[2], pa[3], kk1, Asn + 8192, tid);
        __builtin_amdgcn_sched_barrier(0);
        __builtin_amdgcn_s_barrier();
        asm volatile("s_waitcnt lgkmcnt(0)" ::: "memory");
        __builtin_amdgcn_sched_barrier(0);
        __builtin_amdgcn_s_setprio(1);
#pragma unroll
        for (int kt = 0; kt < 2; kt++)
#pragma unroll
            for (int i = 0; i < 4; i++)
#pragma unroll
                for (int j = 0; j < 2; j++)
                    acc[i][j] = MFMA_BF16(af[i][kt], bb[j][kt], acc[i][j]);
        __builtin_amdgcn_s_setprio(0);
        __builtin_amdgcn_sched_barrier(0);
        __builtin_amdgcn_s_barrier();

        // ---------- phase q1: read B[2-3]; stage B1(t+1); mfma (m0,n1)
        __builtin_amdgcn_sched_barrier(0);
#pragma unroll
        for (int j = 2; j < 4; j++)
#pragma unroll
            for (int kt = 0; kt < 2; kt++)
                bb[j][kt] = *(const bf16x8*)&Bb[(lrB + j * 16 + c) * 64 + (((kt * 4 + quad) ^ fxor) * 8)];
        if (t + 1 < NT) stage_half(pb[2], pb[3], kk1, Bsn + 8192, tid);
        __builtin_amdgcn_sched_barrier(0);
        __builtin_amdgcn_s_barrier();
        asm volatile("s_waitcnt lgkmcnt(0)" ::: "memory");
        __builtin_amdgcn_sched_barrier(0);
        __builtin_amdgcn_s_setprio(1);
#pragma unroll
        for (int kt = 0; kt < 2; kt++)
#pragma unroll
            for (int i = 0; i < 4; i++)
#pragma unroll
                for (int j = 2; j < 4; j++)
                    acc[i][j] = MFMA_BF16(af[i][kt], bb[j][kt], acc[i][j]);
        __builtin_amdgcn_s_setprio(0);
        __builtin_amdgcn_sched_barrier(0);
        __builtin_amdgcn_s_barrier();

        // ---------- phase q2: read A[4-7]; stage B0(t+2); mfma (m1,n0)
        __builtin_amdgcn_sched_barrier(0);
#pragma unroll
        for (int m = 0; m < 4; m++)
#pragma unroll
            for (int kt = 0; kt < 2; kt++)
                af[m][kt] = *(const bf16x8*)&Ab[((m + 4) * 16 + c) * 64 + (((kt * 4 + quad) ^ fxor) * 8)];
        if (t + 2 < NT) stage_half(pb[0], pb[1], kk2, Bsc, tid);
        __builtin_amdgcn_sched_barrier(0);
        __builtin_amdgcn_s_barrier();
        asm volatile("s_waitcnt lgkmcnt(0)" ::: "memory");
        __builtin_amdgcn_sched_barrier(0);
        __builtin_amdgcn_s_setprio(1);
#pragma unroll
        for (int kt = 0; kt < 2; kt++)
#pragma unroll
            for (int i = 0; i < 4; i++)
#pragma unroll
                for (int j = 0; j < 2; j++)
                    acc[i + 4][j] = MFMA_BF16(af[i][kt], bb[j][kt], acc[i + 4][j]);
        __builtin_amdgcn_s_setprio(0);
        __builtin_amdgcn_sched_barrier(0);
        __builtin_amdgcn_s_barrier();

        // ---------- phase q3: stage A0(t+2); vmcnt(4); mfma (m1,n1)
        __builtin_amdgcn_sched_barrier(0);
        if (t + 2 < NT) {
            stage_half(pa[0], pa[1], kk2, Asc, tid);
            asm volatile("s_waitcnt vmcnt(4)" ::: "memory");
        } else if (t + 1 < NT) {
            asm volatile("s_waitcnt vmcnt(0)" ::: "memory");
        }
        __builtin_amdgcn_sched_barrier(0);
        __builtin_amdgcn_s_barrier();
        __builtin_amdgcn_sched_barrier(0);
        __builtin_amdgcn_s_setprio(1);
#pragma unroll
        for (int kt = 0; kt < 2; kt++)
#pragma unroll
            for (int i = 0; i < 4; i++)
#pragma unroll
                for (int j = 2; j < 4; j++)
                    acc[i + 4][j] = MFMA_BF16(af[i][kt], bb[j][kt], acc[i + 4][j]);
        __builtin_amdgcn_s_setprio(0);
        __builtin_amdgcn_sched_barrier(0);
        __builtin_amdgcn_s_barrier();
    }

#pragma unroll
    for (int j = 0; j < 4; j++) {
        int col = n0 + wc * 64 + j * 16 + c;
        if (col >= N) continue;
        float bv = bias ? bias[col] : 0.0f;
#pragma unroll
        for (int i = 0; i < 8; i++) {
            int row = m0 + wr * 128 + i * 16 + quad * 4;
#pragma unroll
            for (int r = 0; r < 4; r++)
                C[(size_t)(row + r) * N + col] = (__bf16)(acc[i][j][r] + bv);
        }
    }
}

// Fused QKV, whole-K: grid (8,20); XCD-swizzled (160 = 8 x 20 bijective).
__global__ __launch_bounds__(512, 2) void qkv_kernel(
    const __bf16* __restrict__ x,
    const __bf16* __restrict__ wq, const float* __restrict__ bq,
    const __bf16* __restrict__ wk, const float* __restrict__ bk,
    const __bf16* __restrict__ wv, const float* __restrict__ bv,
    __bf16* __restrict__ qo, __bf16* __restrict__ ko, __bf16* __restrict__ vo)
{
    __shared__ __align__(16) __bf16 As[2 * 16384], Bs[2 * 16384];  // 128 KiB
    const int lin = blockIdx.y * 8 + blockIdx.x;        // 0..159
    const int wg  = (lin & 7) * 20 + (lin >> 3);        // XCD-contiguous chunks
    const int m0  = (wg & 7) * 256;
    const int by2 = wg >> 3;                            // 0..19
    const __bf16 *W; const float* bias; __bf16* C; int N, n0;
    if (by2 < 16)      { W = wq; bias = bq; C = qo; N = 4096; n0 = by2 * 256; }
    else if (by2 < 18) { W = wk; bias = bk; C = ko; N = 512;  n0 = (by2 - 16) * 256; }
    else               { W = wv; bias = bv; C = vo; N = 512;  n0 = (by2 - 18) * 256; }
    gemm256(x, W, bias, C, N, 2880, 0, 2880, m0, n0, As, Bs);
}

// O-proj split-K=2 partials (r2 128x128): grid (16,23,2); XCD swizzle 368=8x46.
__global__ __launch_bounds__(256, 3) void oproj_kernel(
    const __bf16* __restrict__ a, const __bf16* __restrict__ w,
    __bf16* __restrict__ p0, __bf16* __restrict__ p1)
{
    __shared__ __align__(16) __bf16 As[8192], Bs[8192];
    const int z = blockIdx.z;
    __bf16* C = z ? p1 : p0;
    const int orig = blockIdx.y * 16 + blockIdx.x;
    const int wg   = (orig & 7) * 46 + (orig >> 3);
    const int bx   = wg & 15;
    const int by   = wg >> 4;
    gemm_block64(a, w, nullptr, C, 2880, 4096, z * 2048, (z + 1) * 2048,
                 bx * 128, by * 128, As, Bs);
}

// out[e] = p0[e] + p1[e] + bias[col]; 8 elems/thread, grid 2880x256 exact.
__global__ __launch_bounds__(256) void reduce_kernel(
    const __bf16* __restrict__ p0, const __bf16* __restrict__ p1,
    const float* __restrict__ bo, float* __restrict__ out)
{
    long e = ((long)blockIdx.x * 256 + threadIdx.x) * 8;
    int col = (int)(e % 2880L);          // 2880 % 8 == 0: no row crossing
    bf16x8 a = *(const bf16x8*)(p0 + e);
    bf16x8 b = *(const bf16x8*)(p1 + e);
    f32x4 o0, o1;
#pragma unroll
    for (int t = 0; t < 4; t++) {
        o0[t] = (float)a[t]     + (float)b[t]     + bo[col + t];
        o1[t] = (float)a[4 + t] + (float)b[4 + t] + bo[col + 4 + t];
    }
    *(f32x4*)(out + e)     = o0;
    *(f32x4*)(out + e + 4) = o1;
}

// ---------------------------------------------------------------------------
// Attention f-step, F = 0..3 compile-time. All array indices static.
// acc9[jj] = S[key (F+jj)*16+quad*4+r][q = c] (swapped QK^T), softmax in
// lane-column group {c,c+16,c+32,c+48}, sink factor folded into P, P
// redistributed to PV A-frags via pack2 + shfl.
// ---------------------------------------------------------------------------
template<int F>
__device__ __forceinline__ void attn_f_step(
    const __bf16* __restrict__ Ks, const __bf16* __restrict__ Vt,
    __bf16* __restrict__ q, bf16x8 qf0, bf16x8 qf1,
    int i0, int h, int k0, float sk,
    int c, int quad, int laneA, int laneB, bool hiSel, int db)
{
    // ---- swapped QK^T
    f32x4 acc9[9];
#pragma unroll
    for (int jj = 0; jj < 9; jj++) acc9[jj] = (f32x4){0.f, 0.f, 0.f, 0.f};
    __builtin_amdgcn_s_setprio(1);
#pragma unroll
    for (int jj = 0; jj < 9; jj++) {
        const int j = F + jj;
        bf16x8 kf0 = *(const bf16x8*)&Ks[(j * 16 + c) * 72 + quad * 8];
        bf16x8 kf1 = *(const bf16x8*)&Ks[(j * 16 + c) * 72 + 32 + quad * 8];
        acc9[jj] = MFMA_BF16(kf0, qf0, acc9[jj]);
        acc9[jj] = MFMA_BF16(kf1, qf1, acc9[jj]);
    }
    __builtin_amdgcn_s_setprio(0);

    // ---- mask + row max (d = ig - jg; valid iff 0<=d<128 && jg>=0)
    const int jgb = k0 + F * 16 + quad * 4;
    float rmax = -3.0e4f;
#pragma unroll
    for (int jj = 0; jj < 9; jj++)
#pragma unroll
        for (int r = 0; r < 4; r++) {
            int d  = db  - jj * 16 - r;
            int jg = jgb + jj * 16 + r;
            bool ok = ((unsigned)d < 128u) && (jg >= 0);
            float vv = ok ? acc9[jj][r] : -3.0e4f;
            acc9[jj][r] = vv;
            rmax = fmaxf(rmax, vv);
        }
    rmax = fmaxf(rmax, __shfl_xor(rmax, 16));
    rmax = fmaxf(rmax, __shfl_xor(rmax, 32));

    float rs = 0.f;
#pragma unroll
    for (int jj = 0; jj < 9; jj++)
#pragma unroll
        for (int r = 0; r < 4; r++) {
            float e = __expf(acc9[jj][r] - rmax);
            acc9[jj][r] = e;
            rs += e;
        }
    rs += __shfl_xor(rs, 16);
    rs += __shfl_xor(rs, 32);

    // rowfac = sigmoid(lse - sink) / rowsum, folded into P
    float s   = fmaxf(rs, 1e-20f);
    float lse = rmax + __logf(s);
    float fac = 1.f / ((1.f + __expf(sk - lse)) * s);

    // ---- pack P*fac to bf16 pairs into static 20-word window
    uint32_t pk[20];
#pragma unroll
    for (int t = 0; t < 20; t++) pk[t] = 0;
#pragma unroll
    for (int jj = 0; jj < 9; jj++) {
        const int li = (F & 1) ? (2 * jj + 2) : (2 * jj);
        pk[li]     = pack2(acc9[jj][0] * fac, acc9[jj][1] * fac);
        pk[li + 1] = pack2(acc9[jj][2] * fac, acc9[jj][3] * fac);
    }

    // ---- PV: rebuild A-frags via shfl (within {c,c+16,c+32,c+48})
    f32x4 acc2[4];
#pragma unroll
    for (int jd = 0; jd < 4; jd++) acc2[jd] = (f32x4){0.f, 0.f, 0.f, 0.f};
#pragma unroll
    for (int kk = 0; kk < 5; kk++) {
        const int kt = (F >> 1) + kk;        // Vt chunk (global)
        uint32_t l0  = (uint32_t)__shfl((int)pk[4 * kk],     laneA);
        uint32_t h0  = (uint32_t)__shfl((int)pk[4 * kk + 1], laneA);
        uint32_t l0b = (uint32_t)__shfl((int)pk[4 * kk],     laneB);
        uint32_t h0b = (uint32_t)__shfl((int)pk[4 * kk + 1], laneB);
        uint32_t l1  = (uint32_t)__shfl((int)pk[4 * kk + 2], laneA);
        uint32_t h1  = (uint32_t)__shfl((int)pk[4 * kk + 3], laneA);
        uint32_t l1b = (uint32_t)__shfl((int)pk[4 * kk + 2], laneB);
        uint32_t h1b = (uint32_t)__shfl((int)pk[4 * kk + 3], laneB);
        u32x4 wvv = { hiSel ? l1  : l0,  hiSel ? h1  : h0,
                      hiSel ? l1b : l0b, hiSel ? h1b : h0b };
        bf16x8 pa = __builtin_bit_cast(bf16x8, wvv);
        __builtin_amdgcn_s_setprio(1);
#pragma unroll
        for (int jd = 0; jd < 4; jd++) {
            bf16x8 bv = *(const bf16x8*)&Vt[(jd * 16 + c) * 200 + kt * 32 + quad * 8];
            acc2[jd] = MFMA_BF16(pa, bv, acc2[jd]);
        }
        __builtin_amdgcn_s_setprio(0);
    }

    // ---- store O rows of this F (sink factor already folded into P)
#pragma unroll
    for (int jd = 0; jd < 4; jd++)
#pragma unroll
        for (int r = 0; r < 4; r++)
            q[(size_t)(i0 + F * 16 + quad * 4 + r) * 4096 + h * 64 + jd * 16 + c]
                = (__bf16)acc2[jd][r];
}

// ---------------------------------------------------------------------------
// Attention, fused RoPE, in-place on q. Grid (32 q-tiles, 8 kv-heads),
// 512 threads = 8 waves; wave w = head kvh*8+w, all 64 rows of the tile.
// K (rope'd) and V^T staged ONCE per block (shared by 8 heads).
// LDS: Ks[192][72] (2-way bank), Vt[64][200] (2-way bank) = 53KB.
// ---------------------------------------------------------------------------
__global__ __launch_bounds__(512) void attn_kernel(
    __bf16* __restrict__ q, const __bf16* __restrict__ k,
    const __bf16* __restrict__ v, const float* __restrict__ sinks,
    const float* __restrict__ rope)
{
    __shared__ __align__(16) __bf16 Ks[192 * 72];
    __shared__ __align__(16) __bf16 Vt[64 * 200];

    const int tid = threadIdx.x, lane = tid & 63, w = tid >> 6;
    const int quad = lane >> 4, c = lane & 15;
    const int i0  = blockIdx.x * 64;
    const int kvh = blockIdx.y;
    const int h   = kvh * 8 + w;
    const int k0  = i0 - 128;
    const float scale = 0.16832169878499658f;   // (0.1*ln32+1)/sqrt(64)

    // ---- stage K with rope: 192 rows x 64 dims, 768 units of 16 elems
#pragma unroll
    for (int it = 0; it < 2; it++) {
        int unit = it * 512 + tid;
        if (unit < 768) {
            int krow = unit >> 2;
            int kdg  = (unit & 3) * 8;
            int j = k0 + krow; if (j < 0) j = 0;
            const __bf16* gp = k + (size_t)j * 512 + kvh * 64 + kdg;
            bf16x8 x1 = *(const bf16x8*)(gp);
            bf16x8 x2 = *(const bf16x8*)(gp + 32);
            const float* rc = rope + (size_t)j * 128 + kdg;
            bf16x8 o1, o2;
#pragma unroll
            for (int t = 0; t < 8; t++) {
                float cc = rc[t], si = rc[64 + t];
                float a = (float)x1[t], b = (float)x2[t];
                o1[t] = (__bf16)(a * cc - b * si);
                o2[t] = (__bf16)(b * cc + a * si);
            }
            *(bf16x8*)&Ks[krow * 72 + kdg]      = o1;
            *(bf16x8*)&Ks[krow * 72 + kdg + 32] = o2;
        }
    }

    // ---- stage V transposed: Vt[d][s]  (s = staged key index)
    {
        const int vrow = tid & 63;
        const int d0   = (tid >> 6) * 8;
#pragma unroll
        for (int it = 0; it < 3; it++) {
            int s = it * 64 + vrow;
            int j = k0 + s; if (j < 0) j = 0;
            bf16x8 t = *(const bf16x8*)(v + (size_t)j * 512 + kvh * 64 + d0);
#pragma unroll
            for (int u = 0; u < 8; u++) Vt[(d0 + u) * 200 + s] = t[u];
        }
    }

    // ---- Q fragments (B-operand layout: row=c), rope + scale folded in
    bf16x8 qf[4][2];
#pragma unroll
    for (int f = 0; f < 4; f++) {
        const int row = i0 + f * 16 + c;
        const __bf16* gp = q + (size_t)row * 4096 + h * 64 + quad * 8;
        bf16x8 x1 = *(const bf16x8*)(gp);
        bf16x8 x2 = *(const bf16x8*)(gp + 32);
        const float* rc = rope + (size_t)row * 128 + quad * 8;
        bf16x8 o1, o2;
#pragma unroll
        for (int t = 0; t < 8; t++) {
            float cc = rc[t] * scale, si = rc[64 + t] * scale;
            float a = (float)x1[t], b = (float)x2[t];
            o1[t] = (__bf16)(a * cc - b * si);
            o2[t] = (__bf16)(b * cc + a * si);
        }
        qf[f][0] = o1; qf[f][1] = o2;
    }

    __syncthreads();

    const float sk   = sinks[h];
    const int laneA  = ((quad & 1) << 5) + c;   // owner quad (quad&1)*2
    const int laneB  = laneA + 16;              // owner quad (quad&1)*2+1
    const bool hiSel = (quad >> 1) != 0;        // needs j = 2kt+1
    const int db     = 128 + c - quad * 4;      // ig - jg, jj/r part removed

    attn_f_step<0>(Ks, Vt, q, qf[0][0], qf[0][1], i0, h, k0, sk, c, quad, laneA, laneB, hiSel, db);
    attn_f_step<1>(Ks, Vt, q, qf[1][0], qf[1][1], i0, h, k0, sk, c, quad, laneA, laneB, hiSel, db);
    attn_f_step<2>(Ks, Vt, q, qf[2][0], qf[2][1], i0, h, k0, sk, c, quad, laneA, laneB, hiSel, db);
    attn_f_step<3>(Ks, Vt, q, qf[3][0], qf[3][1], i0, h, k0, sk, c, quad, laneA, laneB, hiSel, db);
}

// ---------------------------------------------------------------------------
extern "C" void kernel_launch(void* const* d_in, const int* in_sizes, int n_in,
                              void* d_out, int out_size, void* d_ws, size_t ws_size,
                              hipStream_t stream) {
    const float* x    = (const float*)d_in[0];
    const float* rope = (const float*)d_in[1];
    const float* wq   = (const float*)d_in[2];
    const float* bq   = (const float*)d_in[3];
    const float* wk   = (const float*)d_in[4];
    const float* bk   = (const float*)d_in[5];
    const float* wv   = (const float*)d_in[6];
    const float* bv   = (const float*)d_in[7];
    const float* wo   = (const float*)d_in[8];
    const float* bo   = (const float*)d_in[9];
    const float* sk   = (const float*)d_in[10];
    float* out = (float*)d_out;

    __bf16* wsb = (__bf16*)d_ws;
    __bf16* xb  = wsb + XB;
    __bf16* wqb = wsb + WQB;
    __bf16* wkb = wsb + WKB;
    __bf16* wvb = wsb + WVB;
    __bf16* wob = wsb + WOB;
    __bf16* qb  = wsb + QB;
    __bf16* kb  = wsb + KB;
    __bf16* vb  = wsb + VB;
    __bf16* po0 = wsb + 0L;            // oproj partials overlay dead xb/wqb
    __bf16* po1 = wsb + 5898240L;

    convert_kernel<<<15840, 256, 0, stream>>>(x, wq, wk, wv, wo, xb);
    qkv_kernel<<<dim3(8, 20), 512, 0, stream>>>(xb, wqb, bq, wkb, bk, wvb, bv,
                                                qb, kb, vb);
    attn_kernel<<<dim3(32, 8), 512, 0, stream>>>(qb, kb, vb, sk, rope);
    oproj_kernel<<<dim3(16, 23, 2), 256, 0, stream>>>(qb, wob, po0, po1);
    reduce_kernel<<<2880, 256, 0, stream>>>(po0, po1, bo, out);
}

// Round 6
// 328.213 us; speedup vs baseline: 1.1065x; 1.0795x over previous
//
#include <hip/hip_runtime.h>
#include <hip/hip_bf16.h>
#include <math.h>
#include <stdint.h>

// ---------------------------------------------------------------------------
// Attention_17231408791684: x->QKV (bias) -> RoPE -> sliding-window(128)
// causal attention w/ sinks -> O-proj (bias).  f32 in/out, bf16 compute.
// Round 13: kill-switch fired -- qkv reverted to the r2-proven 128x128
// gemm_block64 (+XCD swizzle, 78.7us measured); 256x256 pipeline removed
// (3 rounds: 110/97/96us, all worse than 78.7; schedule hypothesis dead).
// Experiment: attn TLP x2 -- 32-row q-tiles, grid (64,8)=512 blocks = 2
// blocks/CU exactly, 4 waves/SIMD (was 1 block/CU, 2 waves/SIMD). If attn
// was the unattributed ~100us (latency-bound), this halves-or-better it.
// ---------------------------------------------------------------------------

typedef __bf16 bf16x8 __attribute__((ext_vector_type(8)));
typedef float  f32x4  __attribute__((ext_vector_type(4)));
typedef uint32_t u32x4 __attribute__((ext_vector_type(4)));

#define MFMA_BF16(a,b,c) __builtin_amdgcn_mfma_f32_16x16x32_bf16((a),(b),(c),0,0,0)

// workspace element offsets (bf16 elements)
#define XB   0L
#define WQB  5898240L
#define WKB  17694720L
#define WVB  19169280L
#define WOB  20643840L
#define QB   32440320L
#define KB   40828928L
#define VB   41877504L

__device__ __forceinline__ void gld_lds16(const void* g, void* l) {
    __builtin_amdgcn_global_load_lds(
        (__attribute__((address_space(1))) void*)(g),
        (__attribute__((address_space(3))) void*)(l), 16, 0, 0);
}

__device__ __forceinline__ bf16x8 ld8f(const float* p) {
    f32x4 a = *(const f32x4*)p;
    f32x4 b = *(const f32x4*)(p + 4);
    bf16x8 r;
#pragma unroll
    for (int t = 0; t < 4; t++) { r[t] = (__bf16)a[t]; r[t + 4] = (__bf16)b[t]; }
    return r;
}

__device__ __forceinline__ uint32_t pack2(float a, float b) {
    __bf16 x = (__bf16)a, y = (__bf16)b;
    return (uint32_t)__builtin_bit_cast(unsigned short, x)
         | ((uint32_t)__builtin_bit_cast(unsigned short, y) << 16);
}

// ---------------------------------------------------------------------------
// f32 -> bf16 conversion of {x, wq, wk, wv, wo}; 8 elems/thread, 15840x256.
// ---------------------------------------------------------------------------
__global__ __launch_bounds__(256) void convert_kernel(
    const float* __restrict__ x,  const float* __restrict__ wq,
    const float* __restrict__ wk, const float* __restrict__ wv,
    const float* __restrict__ wo, __bf16* __restrict__ dst)
{
    long e = ((long)blockIdx.x * 256 + threadIdx.x) * 8;
    const float* src; long off;
    if      (e <  WQB) { src = x;  off = e; }
    else if (e <  WKB) { src = wq; off = e - WQB; }
    else if (e <  WVB) { src = wk; off = e - WKB; }
    else if (e <  WOB) { src = wv; off = e - WVB; }
    else               { src = wo; off = e - WOB; }
    *(bf16x8*)(dst + e) = ld8f(src + off);
}

// ---------------------------------------------------------------------------
// NT GEMM, BK=64, k in [kBeg,kEnd). 128x128 tile, 256 thr (2x2 waves of
// 64x64). LDS [2][128][32]/operand. bias==nullptr -> none.  (r2-proven)
// ---------------------------------------------------------------------------
__device__ __forceinline__ void gemm_block64(
    const __bf16* __restrict__ A, const __bf16* __restrict__ W,
    const float* __restrict__ bias, __bf16* __restrict__ C,
    int N, int Ks, int kBeg, int kEnd, int m0, int n0,
    __bf16* As, __bf16* Bs)
{
    const int tid  = threadIdx.x;
    const int lane = tid & 63;
    const int wv   = tid >> 6;
    const int wm   = (wv >> 1) * 64;
    const int wn   = (wv & 1) * 64;
    const int quad = lane >> 4;
    const int c    = lane & 15;

    const int srow = tid >> 2;          // 0..63
    const int scol = (tid & 3) * 8;     // 0,8,16,24

    int br0 = n0 + srow;      if (br0 > N - 1) br0 = N - 1;
    int br1 = n0 + 64 + srow; if (br1 > N - 1) br1 = N - 1;
    const __bf16* pa0 = A + (size_t)(m0 + srow) * Ks + scol;
    const __bf16* pa1 = A + (size_t)(m0 + 64 + srow) * Ks + scol;
    const __bf16* pb0 = W + (size_t)br0 * Ks + scol;
    const __bf16* pb1 = W + (size_t)br1 * Ks + scol;

    f32x4 acc[4][4];
#pragma unroll
    for (int i = 0; i < 4; i++)
#pragma unroll
        for (int j = 0; j < 4; j++) acc[i][j] = (f32x4){0.f, 0.f, 0.f, 0.f};

    for (int kk = kBeg; kk < kEnd; kk += 64) {
        gld_lds16(pa0 + kk,      As + tid * 8);
        gld_lds16(pa1 + kk,      As + 2048 + tid * 8);
        gld_lds16(pa0 + kk + 32, As + 4096 + tid * 8);
        gld_lds16(pa1 + kk + 32, As + 6144 + tid * 8);
        gld_lds16(pb0 + kk,      Bs + tid * 8);
        gld_lds16(pb1 + kk,      Bs + 2048 + tid * 8);
        gld_lds16(pb0 + kk + 32, Bs + 4096 + tid * 8);
        gld_lds16(pb1 + kk + 32, Bs + 6144 + tid * 8);
        __syncthreads();
        for (int kt = 0; kt < 2; kt++) {
            bf16x8 af[4], bfv[4];
#pragma unroll
            for (int i = 0; i < 4; i++)
                af[i] = *(const bf16x8*)&As[kt * 4096 + (wm + i * 16 + c) * 32 + quad * 8];
#pragma unroll
            for (int j = 0; j < 4; j++)
                bfv[j] = *(const bf16x8*)&Bs[kt * 4096 + (wn + j * 16 + c) * 32 + quad * 8];
#pragma unroll
            for (int i = 0; i < 4; i++)
#pragma unroll
                for (int j = 0; j < 4; j++)
                    acc[i][j] = MFMA_BF16(af[i], bfv[j], acc[i][j]);
        }
        __syncthreads();
    }

#pragma unroll
    for (int j = 0; j < 4; j++) {
        int col = n0 + wn + j * 16 + c;
        if (col >= N) continue;
        float bv = bias ? bias[col] : 0.0f;
#pragma unroll
        for (int i = 0; i < 4; i++) {
            int row = m0 + wm + i * 16 + quad * 4;
#pragma unroll
            for (int r = 0; r < 4; r++)
                C[(size_t)(row + r) * N + col] = (__bf16)(acc[i][j][r] + bv);
        }
    }
}

// Fused QKV, whole-K: grid (16,40); by<32 -> q, by<36 -> k, else v.
// XCD swizzle: 640 = 8 XCDs x 80 (r2-proven: FETCH 121->73MB, 78.7us).
__global__ __launch_bounds__(256, 3) void qkv_kernel(
    const __bf16* __restrict__ x,
    const __bf16* __restrict__ wq, const float* __restrict__ bq,
    const __bf16* __restrict__ wk, const float* __restrict__ bk,
    const __bf16* __restrict__ wv, const float* __restrict__ bv,
    __bf16* __restrict__ qo, __bf16* __restrict__ ko, __bf16* __restrict__ vo)
{
    __shared__ __align__(16) __bf16 As[8192], Bs[8192];
    const int orig = blockIdx.y * 16 + blockIdx.x;
    const int wg   = (orig & 7) * 80 + (orig >> 3);
    const int bx   = wg & 15;
    const int by   = wg >> 4;
    const __bf16 *W; const float* bias; __bf16* C; int N, n0;
    if (by < 32)      { W = wq; bias = bq; C = qo; N = 4096; n0 = by * 128; }
    else if (by < 36) { W = wk; bias = bk; C = ko; N = 512;  n0 = (by - 32) * 128; }
    else              { W = wv; bias = bv; C = vo; N = 512;  n0 = (by - 36) * 128; }
    gemm_block64(x, W, bias, C, N, 2880, 0, 2880, bx * 128, n0, As, Bs);
}

// O-proj split-K=2 partials: grid (16,23,2); per-z XCD swizzle 368 = 8x46.
__global__ __launch_bounds__(256, 3) void oproj_kernel(
    const __bf16* __restrict__ a, const __bf16* __restrict__ w,
    __bf16* __restrict__ p0, __bf16* __restrict__ p1)
{
    __shared__ __align__(16) __bf16 As[8192], Bs[8192];
    const int z = blockIdx.z;
    __bf16* C = z ? p1 : p0;
    const int orig = blockIdx.y * 16 + blockIdx.x;
    const int wg   = (orig & 7) * 46 + (orig >> 3);
    const int bx   = wg & 15;
    const int by   = wg >> 4;
    gemm_block64(a, w, nullptr, C, 2880, 4096, z * 2048, (z + 1) * 2048,
                 bx * 128, by * 128, As, Bs);
}

// out[e] = p0[e] + p1[e] + bias[col]; 8 elems/thread, grid 2880x256 exact.
__global__ __launch_bounds__(256) void reduce_kernel(
    const __bf16* __restrict__ p0, const __bf16* __restrict__ p1,
    const float* __restrict__ bo, float* __restrict__ out)
{
    long e = ((long)blockIdx.x * 256 + threadIdx.x) * 8;
    int col = (int)(e % 2880L);          // 2880 % 8 == 0: no row crossing
    bf16x8 a = *(const bf16x8*)(p0 + e);
    bf16x8 b = *(const bf16x8*)(p1 + e);
    f32x4 o0, o1;
#pragma unroll
    for (int t = 0; t < 4; t++) {
        o0[t] = (float)a[t]     + (float)b[t]     + bo[col + t];
        o1[t] = (float)a[4 + t] + (float)b[4 + t] + bo[col + 4 + t];
    }
    *(f32x4*)(out + e)     = o0;
    *(f32x4*)(out + e + 4) = o1;
}

// ---------------------------------------------------------------------------
// Attention f-step, F in {0,1} compile-time (32-row q-tile). Static indices.
// acc9[jj] = S[key (F+jj)*16+quad*4+r][q = c] (swapped QK^T), softmax in
// lane-column group {c,c+16,c+32,c+48}, sink factor folded into P, P
// redistributed to PV A-frags via pack2 + shfl.  Mask term
// d = 128+c-quad*4 - jj*16 - r is F/i0-invariant (verified r1-r5).
// ---------------------------------------------------------------------------
template<int F>
__device__ __forceinline__ void attn_f_step(
    const __bf16* __restrict__ Ks, const __bf16* __restrict__ Vt,
    __bf16* __restrict__ q, bf16x8 qf0, bf16x8 qf1,
    int i0, int h, int k0, float sk,
    int c, int quad, int laneA, int laneB, bool hiSel, int db)
{
    // ---- swapped QK^T
    f32x4 acc9[9];
#pragma unroll
    for (int jj = 0; jj < 9; jj++) acc9[jj] = (f32x4){0.f, 0.f, 0.f, 0.f};
    __builtin_amdgcn_s_setprio(1);
#pragma unroll
    for (int jj = 0; jj < 9; jj++) {
        const int j = F + jj;
        bf16x8 kf0 = *(const bf16x8*)&Ks[(j * 16 + c) * 72 + quad * 8];
        bf16x8 kf1 = *(const bf16x8*)&Ks[(j * 16 + c) * 72 + 32 + quad * 8];
        acc9[jj] = MFMA_BF16(kf0, qf0, acc9[jj]);
        acc9[jj] = MFMA_BF16(kf1, qf1, acc9[jj]);
    }
    __builtin_amdgcn_s_setprio(0);

    // ---- mask + row max (d = ig - jg; valid iff 0<=d<128 && jg>=0)
    const int jgb = k0 + F * 16 + quad * 4;
    float rmax = -3.0e4f;
#pragma unroll
    for (int jj = 0; jj < 9; jj++)
#pragma unroll
        for (int r = 0; r < 4; r++) {
            int d  = db  - jj * 16 - r;
            int jg = jgb + jj * 16 + r;
            bool ok = ((unsigned)d < 128u) && (jg >= 0);
            float vv = ok ? acc9[jj][r] : -3.0e4f;
            acc9[jj][r] = vv;
            rmax = fmaxf(rmax, vv);
        }
    rmax = fmaxf(rmax, __shfl_xor(rmax, 16));
    rmax = fmaxf(rmax, __shfl_xor(rmax, 32));

    float rs = 0.f;
#pragma unroll
    for (int jj = 0; jj < 9; jj++)
#pragma unroll
        for (int r = 0; r < 4; r++) {
            float e = __expf(acc9[jj][r] - rmax);
            acc9[jj][r] = e;
            rs += e;
        }
    rs += __shfl_xor(rs, 16);
    rs += __shfl_xor(rs, 32);

    // rowfac = sigmoid(lse - sink) / rowsum, folded into P
    float s   = fmaxf(rs, 1e-20f);
    float lse = rmax + __logf(s);
    float fac = 1.f / ((1.f + __expf(sk - lse)) * s);

    // ---- pack P*fac to bf16 pairs into static 20-word window
    // global word 2j -> local (F even ? 2jj : 2jj+2); pads are masked zeros
    uint32_t pk[20];
#pragma unroll
    for (int t = 0; t < 20; t++) pk[t] = 0;
#pragma unroll
    for (int jj = 0; jj < 9; jj++) {
        const int li = (F & 1) ? (2 * jj + 2) : (2 * jj);
        pk[li]     = pack2(acc9[jj][0] * fac, acc9[jj][1] * fac);
        pk[li + 1] = pack2(acc9[jj][2] * fac, acc9[jj][3] * fac);
    }

    // ---- PV: rebuild A-frags via shfl (within {c,c+16,c+32,c+48})
    f32x4 acc2[4];
#pragma unroll
    for (int jd = 0; jd < 4; jd++) acc2[jd] = (f32x4){0.f, 0.f, 0.f, 0.f};
#pragma unroll
    for (int kk = 0; kk < 5; kk++) {
        const int kt = (F >> 1) + kk;        // Vt chunk (F<2 -> kt = kk)
        uint32_t l0  = (uint32_t)__shfl((int)pk[4 * kk],     laneA);
        uint32_t h0  = (uint32_t)__shfl((int)pk[4 * kk + 1], laneA);
        uint32_t l0b = (uint32_t)__shfl((int)pk[4 * kk],     laneB);
        uint32_t h0b = (uint32_t)__shfl((int)pk[4 * kk + 1], laneB);
        uint32_t l1  = (uint32_t)__shfl((int)pk[4 * kk + 2], laneA);
        uint32_t h1  = (uint32_t)__shfl((int)pk[4 * kk + 3], laneA);
        uint32_t l1b = (uint32_t)__shfl((int)pk[4 * kk + 2], laneB);
        uint32_t h1b = (uint32_t)__shfl((int)pk[4 * kk + 3], laneB);
        u32x4 wvv = { hiSel ? l1  : l0,  hiSel ? h1  : h0,
                      hiSel ? l1b : l0b, hiSel ? h1b : h0b };
        bf16x8 pa = __builtin_bit_cast(bf16x8, wvv);
        __builtin_amdgcn_s_setprio(1);
#pragma unroll
        for (int jd = 0; jd < 4; jd++) {
            bf16x8 bv = *(const bf16x8*)&Vt[(jd * 16 + c) * 168 + kt * 32 + quad * 8];
            acc2[jd] = MFMA_BF16(pa, bv, acc2[jd]);
        }
        __builtin_amdgcn_s_setprio(0);
    }

    // ---- store O rows of this F (sink factor already folded into P)
#pragma unroll
    for (int jd = 0; jd < 4; jd++)
#pragma unroll
        for (int r = 0; r < 4; r++)
            q[(size_t)(i0 + F * 16 + quad * 4 + r) * 4096 + h * 64 + jd * 16 + c]
                = (__bf16)acc2[jd][r];
}

// ---------------------------------------------------------------------------
// Attention, fused RoPE, in-place on q. Grid (64 q-tiles of 32 rows, 8
// kv-heads), 512 threads = 8 waves; wave w = head kvh*8+w, all 32 rows.
// 512 blocks = 2/CU exactly -> 16 waves/CU = 4/SIMD (2x TLP vs r2).
// K (rope'd, 160 rows) and V^T staged ONCE per block (shared by 8 heads).
// LDS: Ks[160][72] (2-way bank) + Vt[64][168] (2-way) = 44.5KB.
// ---------------------------------------------------------------------------
__global__ __launch_bounds__(512) void attn_kernel(
    __bf16* __restrict__ q, const __bf16* __restrict__ k,
    const __bf16* __restrict__ v, const float* __restrict__ sinks,
    const float* __restrict__ rope)
{
    __shared__ __align__(16) __bf16 Ks[160 * 72];
    __shared__ __align__(16) __bf16 Vt[64 * 168];

    const int tid = threadIdx.x, lane = tid & 63, w = tid >> 6;
    const int quad = lane >> 4, c = lane & 15;
    const int i0  = blockIdx.x * 32;
    const int kvh = blockIdx.y;
    const int h   = kvh * 8 + w;
    const int k0  = i0 - 128;
    const float scale = 0.16832169878499658f;   // (0.1*ln32+1)/sqrt(64)

    // ---- stage K with rope: 160 rows x 64 dims, 640 units of 16 elems
#pragma unroll
    for (int it = 0; it < 2; it++) {
        int unit = it * 512 + tid;
        if (unit < 640) {
            int krow = unit >> 2;
            int kdg  = (unit & 3) * 8;
            int j = k0 + krow; if (j < 0) j = 0;
            const __bf16* gp = k + (size_t)j * 512 + kvh * 64 + kdg;
            bf16x8 x1 = *(const bf16x8*)(gp);
            bf16x8 x2 = *(const bf16x8*)(gp + 32);
            const float* rc = rope + (size_t)j * 128 + kdg;
            bf16x8 o1, o2;
#pragma unroll
            for (int t = 0; t < 8; t++) {
                float cc = rc[t], si = rc[64 + t];
                float a = (float)x1[t], b = (float)x2[t];
                o1[t] = (__bf16)(a * cc - b * si);
                o2[t] = (__bf16)(b * cc + a * si);
            }
            *(bf16x8*)&Ks[krow * 72 + kdg]      = o1;
            *(bf16x8*)&Ks[krow * 72 + kdg + 32] = o2;
        }
    }

    // ---- stage V transposed: Vt[d][s], s in [0,160)
    {
        const int vrow = tid & 63;
        const int d0   = (tid >> 6) * 8;
#pragma unroll
        for (int it = 0; it < 3; it++) {
            int s = it * 64 + vrow;
            if (s < 160) {
                int j = k0 + s; if (j < 0) j = 0;
                bf16x8 t = *(const bf16x8*)(v + (size_t)j * 512 + kvh * 64 + d0);
#pragma unroll
                for (int u = 0; u < 8; u++) Vt[(d0 + u) * 168 + s] = t[u];
            }
        }
    }

    // ---- Q fragments (B-operand layout: row=c), rope + scale folded in
    bf16x8 qf[2][2];
#pragma unroll
    for (int f = 0; f < 2; f++) {
        const int row = i0 + f * 16 + c;
        const __bf16* gp = q + (size_t)row * 4096 + h * 64 + quad * 8;
        bf16x8 x1 = *(const bf16x8*)(gp);
        bf16x8 x2 = *(const bf16x8*)(gp + 32);
        const float* rc = rope + (size_t)row * 128 + quad * 8;
        bf16x8 o1, o2;
#pragma unroll
        for (int t = 0; t < 8; t++) {
            float cc = rc[t] * scale, si = rc[64 + t] * scale;
            float a = (float)x1[t], b = (float)x2[t];
            o1[t] = (__bf16)(a * cc - b * si);
            o2[t] = (__bf16)(b * cc + a * si);
        }
        qf[f][0] = o1; qf[f][1] = o2;
    }

    __syncthreads();

    const float sk   = sinks[h];
    const int laneA  = ((quad & 1) << 5) + c;   // owner quad (quad&1)*2
    const int laneB  = laneA + 16;              // owner quad (quad&1)*2+1
    const bool hiSel = (quad >> 1) != 0;        // needs j = 2kt+1
    const int db     = 128 + c - quad * 4;      // ig - jg, jj/r part removed

    attn_f_step<0>(Ks, Vt, q, qf[0][0], qf[0][1], i0, h, k0, sk, c, quad, laneA, laneB, hiSel, db);
    attn_f_step<1>(Ks, Vt, q, qf[1][0], qf[1][1], i0, h, k0, sk, c, quad, laneA, laneB, hiSel, db);
}

// ---------------------------------------------------------------------------
extern "C" void kernel_launch(void* const* d_in, const int* in_sizes, int n_in,
                              void* d_out, int out_size, void* d_ws, size_t ws_size,
                              hipStream_t stream) {
    const float* x    = (const float*)d_in[0];
    const float* rope = (const float*)d_in[1];
    const float* wq   = (const float*)d_in[2];
    const float* bq   = (const float*)d_in[3];
    const float* wk   = (const float*)d_in[4];
    const float* bk   = (const float*)d_in[5];
    const float* wv   = (const float*)d_in[6];
    const float* bv   = (const float*)d_in[7];
    const float* wo   = (const float*)d_in[8];
    const float* bo   = (const float*)d_in[9];
    const float* sk   = (const float*)d_in[10];
    float* out = (float*)d_out;

    __bf16* wsb = (__bf16*)d_ws;
    __bf16* xb  = wsb + XB;
    __bf16* wqb = wsb + WQB;
    __bf16* wkb = wsb + WKB;
    __bf16* wvb = wsb + WVB;
    __bf16* wob = wsb + WOB;
    __bf16* qb  = wsb + QB;
    __bf16* kb  = wsb + KB;
    __bf16* vb  = wsb + VB;
    __bf16* po0 = wsb + 0L;            // oproj partials overlay dead xb/wqb
    __bf16* po1 = wsb + 5898240L;

    convert_kernel<<<15840, 256, 0, stream>>>(x, wq, wk, wv, wo, xb);
    qkv_kernel<<<dim3(16, 40), 256, 0, stream>>>(xb, wqb, bq, wkb, bk, wvb, bv,
                                                 qb, kb, vb);
    attn_kernel<<<dim3(64, 8), 512, 0, stream>>>(qb, kb, vb, sk, rope);
    oproj_kernel<<<dim3(16, 23, 2), 256, 0, stream>>>(qb, wob, po0, po1);
    reduce_kernel<<<2880, 256, 0, stream>>>(po0, po1, bo, out);
}